// Round 12
// baseline (1161.514 us; speedup 1.0000x reference)
//
#include <hip/hip_runtime.h>
#include <hip/hip_fp16.h>
#include <cstdint>
#include <cstddef>

// ---------------------------------------------------------------------------
// GCN regression. Round 12: multi-node register reuse in fused gather+GEMM.
//   R11: FG kernels issue-bound (VALU 49%, HBM 24%): 128 ds_read_b128 per
//   thread re-reading W for every node. Now each 16-lane group processes R
//   nodes; each W fragment read from LDS feeds R nodes' FMAs -> per-node
//   LDS issue /R, gather gets R independent chains. FG1 R=2, FG2/FG3 R=4.
// ---------------------------------------------------------------------------

#define BKT_LG 10
#define BKT_SZ 1024
#define BIN_CHUNK 2048

__device__ __forceinline__ void f4add(float4& a, const float4& v) {
    a.x += v.x; a.y += v.y; a.z += v.z; a.w += v.w;
}

// load 4 halves (8B) -> float4 ; store float4 -> 4 halves
__device__ __forceinline__ float4 h4tof4(const __half* p) {
    union { uint2 u; __half2 h[2]; } cv;
    cv.u = *(const uint2*)p;
    float2 a = __half22float2(cv.h[0]);
    float2 b = __half22float2(cv.h[1]);
    return make_float4(a.x, a.y, b.x, b.y);
}
__device__ __forceinline__ void f4toh4(__half* p, float4 v) {
    union { uint2 u; __half2 h[2]; } cv;
    cv.h[0] = __floats2half2_rn(v.x, v.y);
    cv.h[1] = __floats2half2_rn(v.z, v.w);
    *(uint2*)p = cv.u;
}

// ---- bucket histogram: bcnt[b] = #edges with dst in bucket b
static __global__ void bhist_kernel(const int* __restrict__ dst, int* __restrict__ bcnt,
                                    int E, int NB) {
    __shared__ int h[128];
    for (int i = threadIdx.x; i < NB; i += 256) h[i] = 0;
    __syncthreads();
    for (int t = blockIdx.x * 256 + threadIdx.x; t < E; t += gridDim.x * 256)
        atomicAdd(&h[dst[t] >> BKT_LG], 1);
    __syncthreads();
    for (int i = threadIdx.x; i < NB; i += 256)
        if (h[i]) atomicAdd(&bcnt[i], h[i]);
}

// ---- exclusive scan of bcnt -> base (NB+1), bfill = base  (single block)
static __global__ void bscan_kernel(const int* __restrict__ bcnt, int* __restrict__ base,
                                    int* __restrict__ bfill, int NB, int E) {
    __shared__ int s[128];
    int t = threadIdx.x;
    int v = (t < NB) ? bcnt[t] : 0;
    s[t] = v;
    __syncthreads();
    for (int off = 1; off < 128; off <<= 1) {
        int u = (t >= off) ? s[t - off] : 0;
        __syncthreads();
        s[t] += u;
        __syncthreads();
    }
    if (t < NB) { base[t] = s[t] - v; bfill[t] = s[t] - v; }
    if (t == 0) base[NB] = E;
}

// ---- bin edges into bucket-contiguous runs
__launch_bounds__(256)
static __global__ void bin_kernel(const int* __restrict__ src, const int* __restrict__ dst,
                                  int* __restrict__ bfill, unsigned* __restrict__ binned,
                                  int E, int NB) {
    __shared__ int h[128];
    __shared__ int res[128];
    const int beg = blockIdx.x * BIN_CHUNK;
    const int ce = min(BIN_CHUNK, E - beg);
    for (int i = threadIdx.x; i < NB; i += 256) h[i] = 0;
    __syncthreads();
    for (int i = threadIdx.x; i < ce; i += 256)
        atomicAdd(&h[dst[beg + i] >> BKT_LG], 1);
    __syncthreads();
    for (int i = threadIdx.x; i < NB; i += 256) {
        res[i] = h[i] ? atomicAdd(&bfill[i], h[i]) : 0;
        h[i] = 0;
    }
    __syncthreads();
    for (int i = threadIdx.x; i < ce; i += 256) {
        int d = dst[beg + i];
        int b = d >> BKT_LG;
        int p = res[b] + atomicAdd(&h[b], 1);
        binned[p] = ((unsigned)src[beg + i] << BKT_LG) | (unsigned)(d & (BKT_SZ - 1));
    }
}

// ---- per-bucket: count per node, scan, emit rowptr/dinv, group col
__launch_bounds__(256)
static __global__ void group_kernel(const unsigned* __restrict__ binned, const int* __restrict__ base,
                                    int* __restrict__ rowptr, int* __restrict__ col,
                                    float* __restrict__ dinv, int N, int E) {
    __shared__ int cnt[BKT_SZ];
    __shared__ int ex[BKT_SZ];
    __shared__ int ps[256];
    const int tid = threadIdx.x;
    const int b = blockIdx.x;
    const int node0 = b << BKT_LG;
    const int nn = min(BKT_SZ, N - node0);
    const int beg = base[b], end = base[b + 1];

    for (int i = tid; i < BKT_SZ; i += 256) cnt[i] = 0;
    __syncthreads();
    for (int i = beg + tid; i < end; i += 256)
        atomicAdd(&cnt[binned[i] & (BKT_SZ - 1)], 1);
    __syncthreads();

    const int b4 = tid * 4;
    int c0 = cnt[b4], c1 = cnt[b4 + 1], c2 = cnt[b4 + 2], c3 = cnt[b4 + 3];
    int s01 = c0 + c1;
    int s = s01 + c2 + c3;
    ps[tid] = s;
    __syncthreads();
    for (int off = 1; off < 256; off <<= 1) {
        int u = (tid >= off) ? ps[tid - off] : 0;
        __syncthreads();
        ps[tid] += u;
        __syncthreads();
    }
    int excl = ps[tid] - s;
    ex[b4]     = excl;
    ex[b4 + 1] = excl + c0;
    ex[b4 + 2] = excl + s01;
    ex[b4 + 3] = excl + s01 + c2;
    __syncthreads();

    for (int i = tid; i < nn; i += 256) {
        rowptr[node0 + i] = beg + ex[i];
        dinv[node0 + i] = rsqrtf((float)cnt[i] + 1.0f);
    }
    if (b == 0 && tid == 0) rowptr[N] = E;
    __syncthreads();

    for (int i = beg + tid; i < end; i += 256) {
        unsigned v = binned[i];
        int dl = v & (BKT_SZ - 1);
        int p = atomicAdd(&ex[dl], 1);
        col[beg + p] = (int)(v >> BKT_LG);
    }
}

// o[row] = (half) x[row] * dinv[row], dim 64
static __global__ void scale_kernel(const float* __restrict__ x, const float* __restrict__ dinv,
                                    __half* __restrict__ o, int N) {
    int t = blockIdx.x * 256 + threadIdx.x;
    if (t >= N * 16) return;
    int row = t >> 4;
    int c = (t & 15) * 4;
    float d = dinv[row];
    float4 v = *(const float4*)&x[(size_t)row * 64 + c];
    v.x *= d; v.y *= d; v.z *= d; v.w *= d;
    f4toh4(&o[(size_t)row * 64 + c], v);
}

// Fused gather(64,fp16) + GEMM(64->OUT), R nodes per 16-lane group.
//   agg_i = dinv*(self + sum hs[src]);  if GBR: relu(agg_i + gbias)
//   GEMM: each W fragment read once from LDS feeds all R nodes' FMAs.
//   GMODE 0: out = relu(acc + obias) -> fp32 ; GMODE 1: out = acc*dinv -> fp16
template <int OUT, int GR, int R, bool GBR, int GMODE>
__launch_bounds__(GR * 16)
static __global__ void fg_kernel(const __half* __restrict__ hs, const int* __restrict__ rowptr,
                                 const int* __restrict__ col, const float* __restrict__ dinv,
                                 const float* __restrict__ gbias, const float* __restrict__ W,
                                 const float* __restrict__ obias, void* __restrict__ outv, int N) {
    constexpr int K = 64;
    constexpr int NT = GR * 16;
    constexpr int CPT = OUT / 16;          // cols per thread: 8 / 4 / 2
    __shared__ float Wl[K * OUT];
    const int tid = threadIdx.x;

    for (int i = tid; i < K * OUT / 4; i += NT)
        ((float4*)Wl)[i] = ((const float4*)W)[i];
    __syncthreads();   // the only barrier: W resident before use

    const int lane = tid & 15;
    const int node0 = (blockIdx.x * GR + (tid >> 4)) * R;
    if (node0 >= N) return;

    float4 r[R];
    float dvs[R];
#pragma unroll
    for (int i = 0; i < R; ++i) {
        const int node = node0 + i;
        if (node >= N) { r[i] = make_float4(0.f, 0.f, 0.f, 0.f); dvs[i] = 0.f; continue; }
        const int beg = rowptr[node];
        const int end = rowptr[node + 1];
        float4 acc = h4tof4(&hs[(size_t)node * K + lane * 4]);  // self loop
        float4 acc2 = make_float4(0.f, 0.f, 0.f, 0.f);
        int e = beg;
        for (; e + 8 <= end; e += 8) {
            int myc = col[e + (lane & 7)];
            float4 v[8];
#pragma unroll
            for (int j = 0; j < 8; ++j) {
                int s = __shfl(myc, j, 16);
                v[j] = h4tof4(&hs[(size_t)s * K + lane * 4]);
            }
            f4add(acc, v[0]); f4add(acc2, v[1]);
            f4add(acc, v[2]); f4add(acc2, v[3]);
            f4add(acc, v[4]); f4add(acc2, v[5]);
            f4add(acc, v[6]); f4add(acc2, v[7]);
        }
        {
            const int m = end - e;  // 0..7
            int myc = (e + (lane & 7) < end) ? col[e + (lane & 7)] : 0;
#pragma unroll
            for (int j = 0; j < 7; ++j) {
                if (j < m) {
                    int s = __shfl(myc, j, 16);
                    float4 vv = h4tof4(&hs[(size_t)s * K + lane * 4]);
                    f4add(acc, vv);
                }
            }
        }
        f4add(acc, acc2);
        float dv = dinv[node];
        dvs[i] = dv;
        float4 rr;
        rr.x = acc.x * dv; rr.y = acc.y * dv; rr.z = acc.z * dv; rr.w = acc.w * dv;
        if (GBR) {
            float4 bv = *(const float4*)&gbias[lane * 4];
            rr.x = fmaxf(rr.x + bv.x, 0.f);
            rr.y = fmaxf(rr.y + bv.y, 0.f);
            rr.z = fmaxf(rr.z + bv.z, 0.f);
            rr.w = fmaxf(rr.w + bv.w, 0.f);
        }
        r[i] = rr;
    }

    // ---- GEMM: W fragments read once, applied to all R nodes
    float oacc[R][CPT];
#pragma unroll
    for (int i = 0; i < R; ++i)
#pragma unroll
        for (int c = 0; c < CPT; ++c) oacc[i][c] = 0.f;

#pragma unroll
    for (int k4 = 0; k4 < 16; ++k4) {
        float4 a[R];
#pragma unroll
        for (int i = 0; i < R; ++i) {
            a[i].x = __shfl(r[i].x, k4, 16);
            a[i].y = __shfl(r[i].y, k4, 16);
            a[i].z = __shfl(r[i].z, k4, 16);
            a[i].w = __shfl(r[i].w, k4, 16);
        }
#pragma unroll
        for (int kk = 0; kk < 4; ++kk) {
            int k = k4 * 4 + kk;
            if (CPT >= 4) {
#pragma unroll
                for (int c = 0; c < CPT / 4; ++c) {
                    float4 w = *(float4*)&Wl[k * OUT + c * 64 + lane * 4];
#pragma unroll
                    for (int i = 0; i < R; ++i) {
                        float av = (kk == 0) ? a[i].x : (kk == 1) ? a[i].y : (kk == 2) ? a[i].z : a[i].w;
                        oacc[i][c * 4 + 0] += av * w.x;
                        oacc[i][c * 4 + 1] += av * w.y;
                        oacc[i][c * 4 + 2] += av * w.z;
                        oacc[i][c * 4 + 3] += av * w.w;
                    }
                }
            } else {
                float2 w = *(float2*)&Wl[k * OUT + lane * 2];
#pragma unroll
                for (int i = 0; i < R; ++i) {
                    float av = (kk == 0) ? a[i].x : (kk == 1) ? a[i].y : (kk == 2) ? a[i].z : a[i].w;
                    oacc[i][0] += av * w.x;
                    oacc[i][1] += av * w.y;
                }
            }
        }
    }

#pragma unroll
    for (int i = 0; i < R; ++i) {
        const int node = node0 + i;
        if (node >= N) continue;
        if (GMODE == 0) {
            float* out = (float*)outv;
#pragma unroll
            for (int c = 0; c < CPT / 4; ++c) {
                float4 bv = *(const float4*)&obias[c * 64 + lane * 4];
                float4 o;
                o.x = fmaxf(oacc[i][c * 4 + 0] + bv.x, 0.f);
                o.y = fmaxf(oacc[i][c * 4 + 1] + bv.y, 0.f);
                o.z = fmaxf(oacc[i][c * 4 + 2] + bv.z, 0.f);
                o.w = fmaxf(oacc[i][c * 4 + 3] + bv.w, 0.f);
                *(float4*)&out[(size_t)node * OUT + c * 64 + lane * 4] = o;
            }
        } else {
            __half* out = (__half*)outv;
            float dv = dvs[i];
            if (CPT >= 4) {
#pragma unroll
                for (int c = 0; c < CPT / 4; ++c) {
                    float4 o;
                    o.x = oacc[i][c * 4 + 0] * dv;
                    o.y = oacc[i][c * 4 + 1] * dv;
                    o.z = oacc[i][c * 4 + 2] * dv;
                    o.w = oacc[i][c * 4 + 3] * dv;
                    f4toh4(&out[(size_t)node * OUT + c * 64 + lane * 4], o);
                }
            } else {
                *(__half2*)&out[(size_t)node * OUT + lane * 2] =
                    __floats2half2_rn(oacc[i][0] * dv, oacc[i][1] * dv);
            }
        }
    }
}

// Fused gather(32,fp16) + b4/relu + dot(Wfc) + segment-mean pooling.
__launch_bounds__(256)
static __global__ void fg4_kernel(const __half* __restrict__ hs, const int* __restrict__ rowptr,
                                  const int* __restrict__ col, const float* __restrict__ dinv,
                                  const float* __restrict__ b4, const float* __restrict__ Wfc,
                                  const int* __restrict__ batch, float* __restrict__ psum,
                                  int* __restrict__ pcnt, int N) {
    constexpr int K = 32;
    __shared__ float wl[32];
    __shared__ float gsum[64];
    __shared__ int gcnt[64];
    __shared__ int sbase;
    const int tid = threadIdx.x;
    if (tid < 32) wl[tid] = Wfc[tid];
    if (tid < 64) { gsum[tid] = 0.f; gcnt[tid] = 0; }
    if (tid == 0) {
        int bi = (int)blockIdx.x * 32;
        if (bi > N - 1) bi = N - 1;
        sbase = batch[bi];
    }
    __syncthreads();

    const int lane = tid & 7;
    const int li = tid >> 3;
    const int node = blockIdx.x * 32 + li;
    float val = 0.f;
    if (node < N) {
        const int beg = rowptr[node];
        const int end = rowptr[node + 1];
        float4 acc = h4tof4(&hs[(size_t)node * K + lane * 4]);  // self loop
        float4 acc2 = make_float4(0.f, 0.f, 0.f, 0.f);
        int e = beg;
        for (; e + 8 <= end; e += 8) {
            int myc = col[e + lane];
            float4 v[8];
#pragma unroll
            for (int j = 0; j < 8; ++j) {
                int s = __shfl(myc, j, 8);
                v[j] = h4tof4(&hs[(size_t)s * K + lane * 4]);
            }
            f4add(acc, v[0]); f4add(acc2, v[1]);
            f4add(acc, v[2]); f4add(acc2, v[3]);
            f4add(acc, v[4]); f4add(acc2, v[5]);
            f4add(acc, v[6]); f4add(acc2, v[7]);
        }
        {
            const int m = end - e;
            int myc = (e + lane < end) ? col[e + lane] : 0;
#pragma unroll
            for (int j = 0; j < 7; ++j) {
                if (j < m) {
                    int s = __shfl(myc, j, 8);
                    float4 vv = h4tof4(&hs[(size_t)s * K + lane * 4]);
                    f4add(acc, vv);
                }
            }
        }
        f4add(acc, acc2);
        float dv = dinv[node];
        float4 bv = *(const float4*)&b4[lane * 4];
        float4 h;
        h.x = fmaxf(acc.x * dv + bv.x, 0.f);
        h.y = fmaxf(acc.y * dv + bv.y, 0.f);
        h.z = fmaxf(acc.z * dv + bv.z, 0.f);
        h.w = fmaxf(acc.w * dv + bv.w, 0.f);
        val = h.x * wl[lane * 4 + 0] + h.y * wl[lane * 4 + 1] +
              h.z * wl[lane * 4 + 2] + h.w * wl[lane * 4 + 3];
    }
    // reduce 8 lanes -> lane 0 of each group
    val += __shfl_xor(val, 1, 8);
    val += __shfl_xor(val, 2, 8);
    val += __shfl_xor(val, 4, 8);
    if (node < N && lane == 0) {
        int g = batch[node];
        int rel = g - sbase;
        if ((unsigned)rel < 64u) {
            atomicAdd(&gsum[rel], val);
            atomicAdd(&gcnt[rel], 1);
        } else {
            unsafeAtomicAdd(&psum[g], val);
            atomicAdd(&pcnt[g], 1);
        }
    }
    __syncthreads();
    if (tid < 64 && gcnt[tid] > 0) {
        unsafeAtomicAdd(&psum[sbase + tid], gsum[tid]);
        atomicAdd(&pcnt[sbase + tid], gcnt[tid]);
    }
}

// out(fp16) = Xin(fp32) @ W * dinv[row]. W fully resident in LDS. (gemm2 only)
template <int K, int OUT, int RT>
__launch_bounds__(256)
static __global__ void gemm_kernel(const float* __restrict__ Xin, const float* __restrict__ W,
                                   const float* __restrict__ dinv, __half* __restrict__ out, int N) {
    constexpr int CT = OUT / 4;
    constexpr int RTH = 256 / CT;
    constexpr int RB = RTH * RT;
    constexpr int KP = K + 4;
    __shared__ float Wl[K * OUT];
    __shared__ float Xl[RB * KP];

    const int tid = threadIdx.x;
    const int row0 = blockIdx.x * RB;

    for (int idx = tid; idx < K * OUT / 4; idx += 256)
        ((float4*)Wl)[idx] = ((const float4*)W)[idx];

    constexpr int KC = K / 4;
    for (int idx = tid; idx < RB * KC; idx += 256) {
        int r = idx / KC;
        int kc = idx - r * KC;
        int g = row0 + r;
        float4 v = (g < N) ? ((const float4*)(Xin + (size_t)g * K))[kc]
                           : make_float4(0.f, 0.f, 0.f, 0.f);
        *(float4*)&Xl[r * KP + kc * 4] = v;
    }
    __syncthreads();

    const int tx = tid % CT, ty = tid / CT;
    const int col0 = tx * 4;
    float4 acc[RT];
#pragma unroll
    for (int i = 0; i < RT; i++) acc[i] = make_float4(0.f, 0.f, 0.f, 0.f);

#pragma unroll 4
    for (int k = 0; k < K; k += 4) {
        float4 w0 = *(float4*)&Wl[(k + 0) * OUT + col0];
        float4 w1 = *(float4*)&Wl[(k + 1) * OUT + col0];
        float4 w2 = *(float4*)&Wl[(k + 2) * OUT + col0];
        float4 w3 = *(float4*)&Wl[(k + 3) * OUT + col0];
#pragma unroll
        for (int i = 0; i < RT; i++) {
            float4 xv = *(float4*)&Xl[(ty * RT + i) * KP + k];
            acc[i].x += xv.x * w0.x + xv.y * w1.x + xv.z * w2.x + xv.w * w3.x;
            acc[i].y += xv.x * w0.y + xv.y * w1.y + xv.z * w2.y + xv.w * w3.y;
            acc[i].z += xv.x * w0.z + xv.y * w1.z + xv.z * w2.z + xv.w * w3.z;
            acc[i].w += xv.x * w0.w + xv.y * w1.w + xv.z * w2.w + xv.w * w3.w;
        }
    }

#pragma unroll
    for (int i = 0; i < RT; i++) {
        int g = row0 + ty * RT + i;
        if (g < N) {
            float d = dinv[g];
            float4 r;
            r.x = acc[i].x * d; r.y = acc[i].y * d;
            r.z = acc[i].z * d; r.w = acc[i].w * d;
            f4toh4(&out[(size_t)g * OUT + col0], r);
        }
    }
}

static __global__ void final_kernel(const float* __restrict__ psum, const int* __restrict__ pcnt,
                                    const float* __restrict__ bfc, float* __restrict__ out, int G) {
    int t = threadIdx.x;
    if (t < G) {
        float c = (float)pcnt[t];
        out[t] = psum[t] / fmaxf(c, 1.f) + bfc[0];
    }
}

extern "C" void kernel_launch(void* const* d_in, const int* in_sizes, int n_in,
                              void* d_out, int out_size, void* d_ws, size_t ws_size,
                              hipStream_t stream) {
    const float* x    = (const float*)d_in[0];
    const int*   ei   = (const int*)d_in[1];
    const int*   batch= (const int*)d_in[2];
    const float* W1   = (const float*)d_in[4];
    const float* b1   = (const float*)d_in[5];
    const float* W2   = (const float*)d_in[6];
    const float* b2   = (const float*)d_in[7];
    const float* W3   = (const float*)d_in[8];
    const float* b3   = (const float*)d_in[9];
    const float* W4   = (const float*)d_in[10];
    const float* b4   = (const float*)d_in[11];
    const float* Wfc  = (const float*)d_in[12];
    const float* bfc  = (const float*)d_in[13];
    float* out = (float*)d_out;

    const int N = in_sizes[0] / 64;
    const int E = in_sizes[1] / 2;
    const int G = out_size;
    const int* srcp = ei;
    const int* dstp = ei + E;
    const int NB = (N + BKT_SZ - 1) >> BKT_LG;   // 98 for N=100k

    // workspace layout (float-sized slots)
    float* wsf = (float*)d_ws;
    const size_t Npad = ((size_t)N + 1023) / 1024 * 1024;
    const size_t Epad = ((size_t)E + 1023) / 1024 * 1024;
    float*    dinv   = wsf;                            // Npad
    int*      rowptr = (int*)(wsf + Npad);             // Npad + 1024
    int*      col    = (int*)(wsf + 2 * Npad + 1024);  // Epad
    unsigned* binned = (unsigned*)((float*)col + Epad);// Epad
    int*      bcnt   = (int*)((float*)binned + Epad);  // 256
    int*      base   = bcnt + 256;                     // 256
    int*      bfill  = base + 256;                     // 256
    float*    psum   = (float*)(bfill + 256);          // 256
    int*      pcnt   = (int*)(psum + 256);             // 256
    __half*   T1h    = (__half*)(psum + 1024);         // Npad*64 halves
    __half*   T2h    = (__half*)((float*)T1h + Npad * 32); // Npad*64 halves
    float*    H1     = (float*)T2h + Npad * 32;        // Npad*128 fp32

    const int gN   = (N + 255) / 256;
    const int gN16 = (N * 16 + 255) / 256;
    const int nbin = (E + BIN_CHUNK - 1) / BIN_CHUNK;
    const int gFG1 = (N + 63) / 64;    // 512 threads, 32 groups x R=2
    const int gFG  = (N + 63) / 64;    // 256 threads, 16 groups x R=4
    const int gFG4 = (N + 31) / 32;

    hipMemsetAsync(bcnt, 0, 256 * sizeof(int), stream);
    hipMemsetAsync(psum, 0, 512 * sizeof(float), stream);

    // ---- CSR build (by dst, col = src) + dinv
    bhist_kernel<<<256, 256, 0, stream>>>(dstp, bcnt, E, NB);
    bscan_kernel<<<1, 128, 0, stream>>>(bcnt, base, bfill, NB, E);
    bin_kernel<<<nbin, 256, 0, stream>>>(srcp, dstp, bfill, binned, E, NB);
    group_kernel<<<NB, 256, 0, stream>>>(binned, base, rowptr, col, dinv, N, E);

    // ---- layer 1: scale(fp16 out), fused gather+GEMM(64->128,+b1,relu) -> H1(fp32)
    scale_kernel<<<gN16, 256, 0, stream>>>(x, dinv, T1h, N);
    fg_kernel<128, 32, 2, false, 0><<<gFG1, 512, 0, stream>>>(T1h, rowptr, col, dinv, nullptr, W1, b1, H1, N);

    // ---- layer 2 GEMM: T2h = (H1 @ W2) * dinv  (fp16 out)
    gemm_kernel<128, 64, 2><<<(N + 31) / 32, 256, 0, stream>>>(H1, W2, dinv, T2h, N);

    // ---- fused gather2(+b2,relu) + GEMM3(64->64, *dinv) -> T1h (fp16)
    fg_kernel<64, 16, 4, true, 1><<<gFG, 256, 0, stream>>>(T2h, rowptr, col, dinv, b2, W3, nullptr, T1h, N);

    // ---- fused gather3(+b3,relu) + GEMM4(64->32, *dinv) -> T2h (fp16, 32-dim)
    fg_kernel<32, 16, 4, true, 1><<<gFG, 256, 0, stream>>>(T1h, rowptr, col, dinv, b3, W4, nullptr, T2h, N);

    // ---- fused gather4(+b4,relu) + fc-dot + pooled segment sums
    fg4_kernel<<<gFG4, 256, 0, stream>>>(T2h, rowptr, col, dinv, b4, Wfc, batch, psum, pcnt, N);

    // ---- final mean + bias
    final_kernel<<<1, 256, 0, stream>>>(psum, pcnt, bfc, out, G);
}

// Round 13
// 605.826 us; speedup vs baseline: 1.9172x; 1.9172x over previous
//
#include <hip/hip_runtime.h>
#include <hip/hip_fp16.h>
#include <cstdint>
#include <cstddef>

// ---------------------------------------------------------------------------
// GCN regression. Round 13: revert R12 spill (VGPR 128 + 1GB scratch traffic
// from R-indexed register arrays). FG1 = exact R11 form (R=1, VGPR 32).
// FG2/FG3 get 2-node W-reuse expressed spill-safely: explicit scalar pairs,
// sequential gathers, one v[8] window live -> each LDS W fragment feeds 2
// nodes, per-node ds_read halves.
// ---------------------------------------------------------------------------

#define BKT_LG 10
#define BKT_SZ 1024
#define BIN_CHUNK 2048

__device__ __forceinline__ void f4add(float4& a, const float4& v) {
    a.x += v.x; a.y += v.y; a.z += v.z; a.w += v.w;
}

__device__ __forceinline__ float4 h4tof4(const __half* p) {
    union { uint2 u; __half2 h[2]; } cv;
    cv.u = *(const uint2*)p;
    float2 a = __half22float2(cv.h[0]);
    float2 b = __half22float2(cv.h[1]);
    return make_float4(a.x, a.y, b.x, b.y);
}
__device__ __forceinline__ void f4toh4(__half* p, float4 v) {
    union { uint2 u; __half2 h[2]; } cv;
    cv.h[0] = __floats2half2_rn(v.x, v.y);
    cv.h[1] = __floats2half2_rn(v.z, v.w);
    *(uint2*)p = cv.u;
}

// ---- bucket histogram
static __global__ void bhist_kernel(const int* __restrict__ dst, int* __restrict__ bcnt,
                                    int E, int NB) {
    __shared__ int h[128];
    for (int i = threadIdx.x; i < NB; i += 256) h[i] = 0;
    __syncthreads();
    for (int t = blockIdx.x * 256 + threadIdx.x; t < E; t += gridDim.x * 256)
        atomicAdd(&h[dst[t] >> BKT_LG], 1);
    __syncthreads();
    for (int i = threadIdx.x; i < NB; i += 256)
        if (h[i]) atomicAdd(&bcnt[i], h[i]);
}

// ---- exclusive scan of bcnt -> base (NB+1), bfill = base
static __global__ void bscan_kernel(const int* __restrict__ bcnt, int* __restrict__ base,
                                    int* __restrict__ bfill, int NB, int E) {
    __shared__ int s[128];
    int t = threadIdx.x;
    int v = (t < NB) ? bcnt[t] : 0;
    s[t] = v;
    __syncthreads();
    for (int off = 1; off < 128; off <<= 1) {
        int u = (t >= off) ? s[t - off] : 0;
        __syncthreads();
        s[t] += u;
        __syncthreads();
    }
    if (t < NB) { base[t] = s[t] - v; bfill[t] = s[t] - v; }
    if (t == 0) base[NB] = E;
}

// ---- bin edges into bucket-contiguous runs
__launch_bounds__(256)
static __global__ void bin_kernel(const int* __restrict__ src, const int* __restrict__ dst,
                                  int* __restrict__ bfill, unsigned* __restrict__ binned,
                                  int E, int NB) {
    __shared__ int h[128];
    __shared__ int res[128];
    const int beg = blockIdx.x * BIN_CHUNK;
    const int ce = min(BIN_CHUNK, E - beg);
    for (int i = threadIdx.x; i < NB; i += 256) h[i] = 0;
    __syncthreads();
    for (int i = threadIdx.x; i < ce; i += 256)
        atomicAdd(&h[dst[beg + i] >> BKT_LG], 1);
    __syncthreads();
    for (int i = threadIdx.x; i < NB; i += 256) {
        res[i] = h[i] ? atomicAdd(&bfill[i], h[i]) : 0;
        h[i] = 0;
    }
    __syncthreads();
    for (int i = threadIdx.x; i < ce; i += 256) {
        int d = dst[beg + i];
        int b = d >> BKT_LG;
        int p = res[b] + atomicAdd(&h[b], 1);
        binned[p] = ((unsigned)src[beg + i] << BKT_LG) | (unsigned)(d & (BKT_SZ - 1));
    }
}

// ---- per-bucket: count per node, scan, emit rowptr/dinv, group col
__launch_bounds__(256)
static __global__ void group_kernel(const unsigned* __restrict__ binned, const int* __restrict__ base,
                                    int* __restrict__ rowptr, int* __restrict__ col,
                                    float* __restrict__ dinv, int N, int E) {
    __shared__ int cnt[BKT_SZ];
    __shared__ int ex[BKT_SZ];
    __shared__ int ps[256];
    const int tid = threadIdx.x;
    const int b = blockIdx.x;
    const int node0 = b << BKT_LG;
    const int nn = min(BKT_SZ, N - node0);
    const int beg = base[b], end = base[b + 1];

    for (int i = tid; i < BKT_SZ; i += 256) cnt[i] = 0;
    __syncthreads();
    for (int i = beg + tid; i < end; i += 256)
        atomicAdd(&cnt[binned[i] & (BKT_SZ - 1)], 1);
    __syncthreads();

    const int b4 = tid * 4;
    int c0 = cnt[b4], c1 = cnt[b4 + 1], c2 = cnt[b4 + 2], c3 = cnt[b4 + 3];
    int s01 = c0 + c1;
    int s = s01 + c2 + c3;
    ps[tid] = s;
    __syncthreads();
    for (int off = 1; off < 256; off <<= 1) {
        int u = (tid >= off) ? ps[tid - off] : 0;
        __syncthreads();
        ps[tid] += u;
        __syncthreads();
    }
    int excl = ps[tid] - s;
    ex[b4]     = excl;
    ex[b4 + 1] = excl + c0;
    ex[b4 + 2] = excl + s01;
    ex[b4 + 3] = excl + s01 + c2;
    __syncthreads();

    for (int i = tid; i < nn; i += 256) {
        rowptr[node0 + i] = beg + ex[i];
        dinv[node0 + i] = rsqrtf((float)cnt[i] + 1.0f);
    }
    if (b == 0 && tid == 0) rowptr[N] = E;
    __syncthreads();

    for (int i = beg + tid; i < end; i += 256) {
        unsigned v = binned[i];
        int dl = v & (BKT_SZ - 1);
        int p = atomicAdd(&ex[dl], 1);
        col[beg + p] = (int)(v >> BKT_LG);
    }
}

// o[row] = (half) x[row] * dinv[row], dim 64
static __global__ void scale_kernel(const float* __restrict__ x, const float* __restrict__ dinv,
                                    __half* __restrict__ o, int N) {
    int t = blockIdx.x * 256 + threadIdx.x;
    if (t >= N * 16) return;
    int row = t >> 4;
    int c = (t & 15) * 4;
    float d = dinv[row];
    float4 v = *(const float4*)&x[(size_t)row * 64 + c];
    v.x *= d; v.y *= d; v.z *= d; v.w *= d;
    f4toh4(&o[(size_t)row * 64 + c], v);
}

// gather one 64-dim fp16 node row slice for this lane (16-lane group), with
// dinv scale [+gbias relu]. Returns the lane's 4 floats; sets dv.
template <bool GBR>
__device__ __forceinline__ float4 gather64(const __half* __restrict__ hs,
                                           const int* __restrict__ rowptr,
                                           const int* __restrict__ col,
                                           const float* __restrict__ dinv,
                                           const float* __restrict__ gbias,
                                           int node, int lane, float& dv) {
    constexpr int K = 64;
    const int beg = rowptr[node];
    const int end = rowptr[node + 1];
    float4 acc = h4tof4(&hs[(size_t)node * K + lane * 4]);  // self loop
    float4 acc2 = make_float4(0.f, 0.f, 0.f, 0.f);
    int e = beg;
    for (; e + 8 <= end; e += 8) {
        int myc = col[e + (lane & 7)];
        float4 v[8];
#pragma unroll
        for (int j = 0; j < 8; ++j) {
            int s = __shfl(myc, j, 16);
            v[j] = h4tof4(&hs[(size_t)s * K + lane * 4]);
        }
        f4add(acc, v[0]); f4add(acc2, v[1]);
        f4add(acc, v[2]); f4add(acc2, v[3]);
        f4add(acc, v[4]); f4add(acc2, v[5]);
        f4add(acc, v[6]); f4add(acc2, v[7]);
    }
    {
        const int m = end - e;  // 0..7
        int myc = (e + (lane & 7) < end) ? col[e + (lane & 7)] : 0;
#pragma unroll
        for (int j = 0; j < 7; ++j) {
            if (j < m) {
                int s = __shfl(myc, j, 16);
                float4 vv = h4tof4(&hs[(size_t)s * K + lane * 4]);
                f4add(acc, vv);
            }
        }
    }
    f4add(acc, acc2);
    dv = dinv[node];
    float4 r;
    r.x = acc.x * dv; r.y = acc.y * dv; r.z = acc.z * dv; r.w = acc.w * dv;
    if (GBR) {
        float4 bv = *(const float4*)&gbias[lane * 4];
        r.x = fmaxf(r.x + bv.x, 0.f);
        r.y = fmaxf(r.y + bv.y, 0.f);
        r.z = fmaxf(r.z + bv.z, 0.f);
        r.w = fmaxf(r.w + bv.w, 0.f);
    }
    return r;
}

// FG1: fused gather(64,fp16) + GEMM(64->128) + b1 + relu -> fp32 H1.
// 32 nodes x 16 lanes = 512 threads. Exact R11 structure (VGPR 32, no spill).
__launch_bounds__(512)
static __global__ void fg1_kernel(const __half* __restrict__ hs, const int* __restrict__ rowptr,
                                  const int* __restrict__ col, const float* __restrict__ dinv,
                                  const float* __restrict__ W, const float* __restrict__ obias,
                                  float* __restrict__ out, int N) {
    constexpr int K = 64;
    constexpr int OUT = 128;
    constexpr int CPT = 8;
    __shared__ float Wl[K * OUT];
    const int tid = threadIdx.x;

    for (int i = tid; i < K * OUT / 4; i += 512)
        ((float4*)Wl)[i] = ((const float4*)W)[i];
    __syncthreads();

    const int lane = tid & 15;
    const int node = blockIdx.x * 32 + (tid >> 4);
    if (node >= N) return;

    float dv;
    float4 r = gather64<false>(hs, rowptr, col, dinv, nullptr, node, lane, dv);

    float oacc[CPT];
#pragma unroll
    for (int c = 0; c < CPT; ++c) oacc[c] = 0.f;

#pragma unroll
    for (int k4 = 0; k4 < 16; ++k4) {
        float4 a;
        a.x = __shfl(r.x, k4, 16);
        a.y = __shfl(r.y, k4, 16);
        a.z = __shfl(r.z, k4, 16);
        a.w = __shfl(r.w, k4, 16);
#pragma unroll
        for (int kk = 0; kk < 4; ++kk) {
            float av = (kk == 0) ? a.x : (kk == 1) ? a.y : (kk == 2) ? a.z : a.w;
            int k = k4 * 4 + kk;
#pragma unroll
            for (int c = 0; c < 2; ++c) {
                float4 w = *(float4*)&Wl[k * OUT + c * 64 + lane * 4];
                oacc[c * 4 + 0] += av * w.x;
                oacc[c * 4 + 1] += av * w.y;
                oacc[c * 4 + 2] += av * w.z;
                oacc[c * 4 + 3] += av * w.w;
            }
        }
    }

#pragma unroll
    for (int c = 0; c < 2; ++c) {
        float4 bv = *(const float4*)&obias[c * 64 + lane * 4];
        float4 o;
        o.x = fmaxf(oacc[c * 4 + 0] + bv.x, 0.f);
        o.y = fmaxf(oacc[c * 4 + 1] + bv.y, 0.f);
        o.z = fmaxf(oacc[c * 4 + 2] + bv.z, 0.f);
        o.w = fmaxf(oacc[c * 4 + 3] + bv.w, 0.f);
        *(float4*)&out[(size_t)node * OUT + c * 64 + lane * 4] = o;
    }
}

// FG2/FG3: fused gather(64,fp16)+gbias+relu + GEMM(64->OUT)*dinv -> fp16.
// 2 nodes per 16-lane group, explicit scalar pairs (spill-safe W reuse):
// each LDS W fragment feeds both nodes. 256 threads = 16 groups x 2 nodes.
template <int OUT>
__launch_bounds__(256)
static __global__ void fg2_kernel(const __half* __restrict__ hs, const int* __restrict__ rowptr,
                                  const int* __restrict__ col, const float* __restrict__ dinv,
                                  const float* __restrict__ gbias, const float* __restrict__ W,
                                  __half* __restrict__ out, int N) {
    constexpr int K = 64;
    constexpr int CPT = OUT / 16;          // 4 or 2
    __shared__ float Wl[K * OUT];
    const int tid = threadIdx.x;

    for (int i = tid; i < K * OUT / 4; i += 256)
        ((float4*)Wl)[i] = ((const float4*)W)[i];
    __syncthreads();

    const int lane = tid & 15;
    const int node0 = blockIdx.x * 32 + (tid >> 4) * 2;
    if (node0 >= N) return;
    const bool has1 = (node0 + 1) < N;

    float dv0, dv1 = 0.f;
    float4 r0 = gather64<true>(hs, rowptr, col, dinv, gbias, node0, lane, dv0);
    float4 r1 = make_float4(0.f, 0.f, 0.f, 0.f);
    if (has1) r1 = gather64<true>(hs, rowptr, col, dinv, gbias, node0 + 1, lane, dv1);

    float oa[CPT], ob[CPT];
#pragma unroll
    for (int c = 0; c < CPT; ++c) { oa[c] = 0.f; ob[c] = 0.f; }

#pragma unroll
    for (int k4 = 0; k4 < 16; ++k4) {
        float4 a0, a1;
        a0.x = __shfl(r0.x, k4, 16); a1.x = __shfl(r1.x, k4, 16);
        a0.y = __shfl(r0.y, k4, 16); a1.y = __shfl(r1.y, k4, 16);
        a0.z = __shfl(r0.z, k4, 16); a1.z = __shfl(r1.z, k4, 16);
        a0.w = __shfl(r0.w, k4, 16); a1.w = __shfl(r1.w, k4, 16);
#pragma unroll
        for (int kk = 0; kk < 4; ++kk) {
            float av0 = (kk == 0) ? a0.x : (kk == 1) ? a0.y : (kk == 2) ? a0.z : a0.w;
            float av1 = (kk == 0) ? a1.x : (kk == 1) ? a1.y : (kk == 2) ? a1.z : a1.w;
            int k = k4 * 4 + kk;
            if (CPT == 4) {
                float4 w = *(float4*)&Wl[k * OUT + lane * 4];
                oa[0] += av0 * w.x; oa[1] += av0 * w.y; oa[2] += av0 * w.z; oa[3] += av0 * w.w;
                ob[0] += av1 * w.x; ob[1] += av1 * w.y; ob[2] += av1 * w.z; ob[3] += av1 * w.w;
            } else {
                float2 w = *(float2*)&Wl[k * OUT + lane * 2];
                oa[0] += av0 * w.x; oa[1] += av0 * w.y;
                ob[0] += av1 * w.x; ob[1] += av1 * w.y;
            }
        }
    }

    if (CPT == 4) {
        float4 o;
        o.x = oa[0] * dv0; o.y = oa[1] * dv0; o.z = oa[2] * dv0; o.w = oa[3] * dv0;
        f4toh4(&out[(size_t)node0 * OUT + lane * 4], o);
        if (has1) {
            o.x = ob[0] * dv1; o.y = ob[1] * dv1; o.z = ob[2] * dv1; o.w = ob[3] * dv1;
            f4toh4(&out[(size_t)(node0 + 1) * OUT + lane * 4], o);
        }
    } else {
        *(__half2*)&out[(size_t)node0 * OUT + lane * 2] =
            __floats2half2_rn(oa[0] * dv0, oa[1] * dv0);
        if (has1)
            *(__half2*)&out[(size_t)(node0 + 1) * OUT + lane * 2] =
                __floats2half2_rn(ob[0] * dv1, ob[1] * dv1);
    }
}

// Fused gather(32,fp16) + b4/relu + dot(Wfc) + segment-mean pooling.
__launch_bounds__(256)
static __global__ void fg4_kernel(const __half* __restrict__ hs, const int* __restrict__ rowptr,
                                  const int* __restrict__ col, const float* __restrict__ dinv,
                                  const float* __restrict__ b4, const float* __restrict__ Wfc,
                                  const int* __restrict__ batch, float* __restrict__ psum,
                                  int* __restrict__ pcnt, int N) {
    constexpr int K = 32;
    __shared__ float wl[32];
    __shared__ float gsum[64];
    __shared__ int gcnt[64];
    __shared__ int sbase;
    const int tid = threadIdx.x;
    if (tid < 32) wl[tid] = Wfc[tid];
    if (tid < 64) { gsum[tid] = 0.f; gcnt[tid] = 0; }
    if (tid == 0) {
        int bi = (int)blockIdx.x * 32;
        if (bi > N - 1) bi = N - 1;
        sbase = batch[bi];
    }
    __syncthreads();

    const int lane = tid & 7;
    const int li = tid >> 3;
    const int node = blockIdx.x * 32 + li;
    float val = 0.f;
    if (node < N) {
        const int beg = rowptr[node];
        const int end = rowptr[node + 1];
        float4 acc = h4tof4(&hs[(size_t)node * K + lane * 4]);
        float4 acc2 = make_float4(0.f, 0.f, 0.f, 0.f);
        int e = beg;
        for (; e + 8 <= end; e += 8) {
            int myc = col[e + lane];
            float4 v[8];
#pragma unroll
            for (int j = 0; j < 8; ++j) {
                int s = __shfl(myc, j, 8);
                v[j] = h4tof4(&hs[(size_t)s * K + lane * 4]);
            }
            f4add(acc, v[0]); f4add(acc2, v[1]);
            f4add(acc, v[2]); f4add(acc2, v[3]);
            f4add(acc, v[4]); f4add(acc2, v[5]);
            f4add(acc, v[6]); f4add(acc2, v[7]);
        }
        {
            const int m = end - e;
            int myc = (e + lane < end) ? col[e + lane] : 0;
#pragma unroll
            for (int j = 0; j < 7; ++j) {
                if (j < m) {
                    int s = __shfl(myc, j, 8);
                    float4 vv = h4tof4(&hs[(size_t)s * K + lane * 4]);
                    f4add(acc, vv);
                }
            }
        }
        f4add(acc, acc2);
        float dv = dinv[node];
        float4 bv = *(const float4*)&b4[lane * 4];
        float4 h;
        h.x = fmaxf(acc.x * dv + bv.x, 0.f);
        h.y = fmaxf(acc.y * dv + bv.y, 0.f);
        h.z = fmaxf(acc.z * dv + bv.z, 0.f);
        h.w = fmaxf(acc.w * dv + bv.w, 0.f);
        val = h.x * wl[lane * 4 + 0] + h.y * wl[lane * 4 + 1] +
              h.z * wl[lane * 4 + 2] + h.w * wl[lane * 4 + 3];
    }
    val += __shfl_xor(val, 1, 8);
    val += __shfl_xor(val, 2, 8);
    val += __shfl_xor(val, 4, 8);
    if (node < N && lane == 0) {
        int g = batch[node];
        int rel = g - sbase;
        if ((unsigned)rel < 64u) {
            atomicAdd(&gsum[rel], val);
            atomicAdd(&gcnt[rel], 1);
        } else {
            unsafeAtomicAdd(&psum[g], val);
            atomicAdd(&pcnt[g], 1);
        }
    }
    __syncthreads();
    if (tid < 64 && gcnt[tid] > 0) {
        unsafeAtomicAdd(&psum[sbase + tid], gsum[tid]);
        atomicAdd(&pcnt[sbase + tid], gcnt[tid]);
    }
}

// out(fp16) = Xin(fp32) @ W * dinv[row]. W fully resident in LDS. (gemm2 only)
template <int K, int OUT, int RT>
__launch_bounds__(256)
static __global__ void gemm_kernel(const float* __restrict__ Xin, const float* __restrict__ W,
                                   const float* __restrict__ dinv, __half* __restrict__ out, int N) {
    constexpr int CT = OUT / 4;
    constexpr int RTH = 256 / CT;
    constexpr int RB = RTH * RT;
    constexpr int KP = K + 4;
    __shared__ float Wl[K * OUT];
    __shared__ float Xl[RB * KP];

    const int tid = threadIdx.x;
    const int row0 = blockIdx.x * RB;

    for (int idx = tid; idx < K * OUT / 4; idx += 256)
        ((float4*)Wl)[idx] = ((const float4*)W)[idx];

    constexpr int KC = K / 4;
    for (int idx = tid; idx < RB * KC; idx += 256) {
        int r = idx / KC;
        int kc = idx - r * KC;
        int g = row0 + r;
        float4 v = (g < N) ? ((const float4*)(Xin + (size_t)g * K))[kc]
                           : make_float4(0.f, 0.f, 0.f, 0.f);
        *(float4*)&Xl[r * KP + kc * 4] = v;
    }
    __syncthreads();

    const int tx = tid % CT, ty = tid / CT;
    const int col0 = tx * 4;
    float4 acc[RT];
#pragma unroll
    for (int i = 0; i < RT; i++) acc[i] = make_float4(0.f, 0.f, 0.f, 0.f);

#pragma unroll 4
    for (int k = 0; k < K; k += 4) {
        float4 w0 = *(float4*)&Wl[(k + 0) * OUT + col0];
        float4 w1 = *(float4*)&Wl[(k + 1) * OUT + col0];
        float4 w2 = *(float4*)&Wl[(k + 2) * OUT + col0];
        float4 w3 = *(float4*)&Wl[(k + 3) * OUT + col0];
#pragma unroll
        for (int i = 0; i < RT; i++) {
            float4 xv = *(float4*)&Xl[(ty * RT + i) * KP + k];
            acc[i].x += xv.x * w0.x + xv.y * w1.x + xv.z * w2.x + xv.w * w3.x;
            acc[i].y += xv.x * w0.y + xv.y * w1.y + xv.z * w2.y + xv.w * w3.y;
            acc[i].z += xv.x * w0.z + xv.y * w1.z + xv.z * w2.z + xv.w * w3.z;
            acc[i].w += xv.x * w0.w + xv.y * w1.w + xv.z * w2.w + xv.w * w3.w;
        }
    }

#pragma unroll
    for (int i = 0; i < RT; i++) {
        int g = row0 + ty * RT + i;
        if (g < N) {
            float d = dinv[g];
            float4 r;
            r.x = acc[i].x * d; r.y = acc[i].y * d;
            r.z = acc[i].z * d; r.w = acc[i].w * d;
            f4toh4(&out[(size_t)g * OUT + col0], r);
        }
    }
}

static __global__ void final_kernel(const float* __restrict__ psum, const int* __restrict__ pcnt,
                                    const float* __restrict__ bfc, float* __restrict__ out, int G) {
    int t = threadIdx.x;
    if (t < G) {
        float c = (float)pcnt[t];
        out[t] = psum[t] / fmaxf(c, 1.f) + bfc[0];
    }
}

extern "C" void kernel_launch(void* const* d_in, const int* in_sizes, int n_in,
                              void* d_out, int out_size, void* d_ws, size_t ws_size,
                              hipStream_t stream) {
    const float* x    = (const float*)d_in[0];
    const int*   ei   = (const int*)d_in[1];
    const int*   batch= (const int*)d_in[2];
    const float* W1   = (const float*)d_in[4];
    const float* b1   = (const float*)d_in[5];
    const float* W2   = (const float*)d_in[6];
    const float* b2   = (const float*)d_in[7];
    const float* W3   = (const float*)d_in[8];
    const float* b3   = (const float*)d_in[9];
    const float* W4   = (const float*)d_in[10];
    const float* b4   = (const float*)d_in[11];
    const float* Wfc  = (const float*)d_in[12];
    const float* bfc  = (const float*)d_in[13];
    float* out = (float*)d_out;

    const int N = in_sizes[0] / 64;
    const int E = in_sizes[1] / 2;
    const int G = out_size;
    const int* srcp = ei;
    const int* dstp = ei + E;
    const int NB = (N + BKT_SZ - 1) >> BKT_LG;   // 98 for N=100k

    // workspace layout (float-sized slots)
    float* wsf = (float*)d_ws;
    const size_t Npad = ((size_t)N + 1023) / 1024 * 1024;
    const size_t Epad = ((size_t)E + 1023) / 1024 * 1024;
    float*    dinv   = wsf;                            // Npad
    int*      rowptr = (int*)(wsf + Npad);             // Npad + 1024
    int*      col    = (int*)(wsf + 2 * Npad + 1024);  // Epad
    unsigned* binned = (unsigned*)((float*)col + Epad);// Epad
    int*      bcnt   = (int*)((float*)binned + Epad);  // 256
    int*      base   = bcnt + 256;                     // 256
    int*      bfill  = base + 256;                     // 256
    float*    psum   = (float*)(bfill + 256);          // 256
    int*      pcnt   = (int*)(psum + 256);             // 256
    __half*   T1h    = (__half*)(psum + 1024);         // Npad*64 halves
    __half*   T2h    = (__half*)((float*)T1h + Npad * 32); // Npad*64 halves
    float*    H1     = (float*)T2h + Npad * 32;        // Npad*128 fp32

    const int gN   = (N + 255) / 256;
    const int gN16 = (N * 16 + 255) / 256;
    const int nbin = (E + BIN_CHUNK - 1) / BIN_CHUNK;
    const int gFG1 = (N + 31) / 32;   // 512 threads, 32 nodes
    const int gFG2 = (N + 31) / 32;   // 256 threads, 16 groups x 2 nodes
    const int gFG4 = (N + 31) / 32;

    hipMemsetAsync(bcnt, 0, 256 * sizeof(int), stream);
    hipMemsetAsync(psum, 0, 512 * sizeof(float), stream);

    // ---- CSR build (by dst, col = src) + dinv
    bhist_kernel<<<256, 256, 0, stream>>>(dstp, bcnt, E, NB);
    bscan_kernel<<<1, 128, 0, stream>>>(bcnt, base, bfill, NB, E);
    bin_kernel<<<nbin, 256, 0, stream>>>(srcp, dstp, bfill, binned, E, NB);
    group_kernel<<<NB, 256, 0, stream>>>(binned, base, rowptr, col, dinv, N, E);

    // ---- layer 1: scale(fp16 out), fused gather+GEMM(64->128,+b1,relu) -> H1(fp32)
    scale_kernel<<<gN16, 256, 0, stream>>>(x, dinv, T1h, N);
    fg1_kernel<<<gFG1, 512, 0, stream>>>(T1h, rowptr, col, dinv, W1, b1, H1, N);

    // ---- layer 2 GEMM: T2h = (H1 @ W2) * dinv  (fp16 out)
    gemm_kernel<128, 64, 2><<<(N + 31) / 32, 256, 0, stream>>>(H1, W2, dinv, T2h, N);

    // ---- fused gather2(+b2,relu) + GEMM3(64->64, *dinv) -> T1h (fp16)
    fg2_kernel<64><<<gFG2, 256, 0, stream>>>(T2h, rowptr, col, dinv, b2, W3, T1h, N);

    // ---- fused gather3(+b3,relu) + GEMM4(64->32, *dinv) -> T2h (fp16, 32-dim)
    fg2_kernel<32><<<gFG2, 256, 0, stream>>>(T1h, rowptr, col, dinv, b3, W4, T2h, N);

    // ---- fused gather4(+b4,relu) + fc-dot + pooled segment sums
    fg4_kernel<<<gFG4, 256, 0, stream>>>(T2h, rowptr, col, dinv, b4, Wfc, batch, psum, pcnt, N);

    // ---- final mean + bias
    final_kernel<<<1, 256, 0, stream>>>(psum, pcnt, bfc, out, G);
}

// Round 15
// 379.769 us; speedup vs baseline: 3.0585x; 1.5952x over previous
//
#include <hip/hip_runtime.h>
#include <hip/hip_fp16.h>
#include <cstdint>
#include <cstddef>

// ---------------------------------------------------------------------------
// GCN regression. Round 14b (type fix of R14: half2v = decltype of
// cvt_pkrtz result). R11 structure + packed-fp16 GEMM phase:
//   W in LDS as packed half2, v_dot2_f32_f16 (2 MAC/inst, fp32 accum)
//   -> FMA 512->256, ds_read 128->64, shfl 64->32 per FG1 thread;
//   LDS 32->16KB. H1 stored fp16 (halves gemm2 traffic).
// ---------------------------------------------------------------------------

#define BKT_LG 10
#define BKT_SZ 1024
#define BIN_CHUNK 2048

using half2v = decltype(__builtin_amdgcn_cvt_pkrtz(0.0f, 0.0f));

#if __has_builtin(__builtin_amdgcn_fdot2)
#define FDOT2(a, b, c) __builtin_amdgcn_fdot2((a), (b), (c), false)
#else
__device__ __forceinline__ float fdot2_emul(half2v a, half2v b, float c) {
    return c + (float)a[0] * (float)b[0] + (float)a[1] * (float)b[1];
}
#define FDOT2(a, b, c) fdot2_emul((a), (b), (c))
#endif

__device__ __forceinline__ half2v i2h(int i) { union { int i; half2v h; } u; u.i = i; return u.h; }
__device__ __forceinline__ int h2i(half2v h) { union { int i; half2v h; } u; u.h = h; return u.i; }
__device__ __forceinline__ int pk2i(float a, float b) { return h2i(__builtin_amdgcn_cvt_pkrtz(a, b)); }

__device__ __forceinline__ void f4add(float4& a, const float4& v) {
    a.x += v.x; a.y += v.y; a.z += v.z; a.w += v.w;
}

__device__ __forceinline__ float4 h4tof4(const __half* p) {
    union { uint2 u; __half2 h[2]; } cv;
    cv.u = *(const uint2*)p;
    float2 a = __half22float2(cv.h[0]);
    float2 b = __half22float2(cv.h[1]);
    return make_float4(a.x, a.y, b.x, b.y);
}
__device__ __forceinline__ void f4toh4(__half* p, float4 v) {
    union { uint2 u; __half2 h[2]; } cv;
    cv.h[0] = __floats2half2_rn(v.x, v.y);
    cv.h[1] = __floats2half2_rn(v.z, v.w);
    *(uint2*)p = cv.u;
}

// ---- bucket histogram
static __global__ void bhist_kernel(const int* __restrict__ dst, int* __restrict__ bcnt,
                                    int E, int NB) {
    __shared__ int h[128];
    for (int i = threadIdx.x; i < NB; i += 256) h[i] = 0;
    __syncthreads();
    for (int t = blockIdx.x * 256 + threadIdx.x; t < E; t += gridDim.x * 256)
        atomicAdd(&h[dst[t] >> BKT_LG], 1);
    __syncthreads();
    for (int i = threadIdx.x; i < NB; i += 256)
        if (h[i]) atomicAdd(&bcnt[i], h[i]);
}

// ---- exclusive scan of bcnt -> base (NB+1), bfill = base
static __global__ void bscan_kernel(const int* __restrict__ bcnt, int* __restrict__ base,
                                    int* __restrict__ bfill, int NB, int E) {
    __shared__ int s[128];
    int t = threadIdx.x;
    int v = (t < NB) ? bcnt[t] : 0;
    s[t] = v;
    __syncthreads();
    for (int off = 1; off < 128; off <<= 1) {
        int u = (t >= off) ? s[t - off] : 0;
        __syncthreads();
        s[t] += u;
        __syncthreads();
    }
    if (t < NB) { base[t] = s[t] - v; bfill[t] = s[t] - v; }
    if (t == 0) base[NB] = E;
}

// ---- bin edges into bucket-contiguous runs
__launch_bounds__(256)
static __global__ void bin_kernel(const int* __restrict__ src, const int* __restrict__ dst,
                                  int* __restrict__ bfill, unsigned* __restrict__ binned,
                                  int E, int NB) {
    __shared__ int h[128];
    __shared__ int res[128];
    const int beg = blockIdx.x * BIN_CHUNK;
    const int ce = min(BIN_CHUNK, E - beg);
    for (int i = threadIdx.x; i < NB; i += 256) h[i] = 0;
    __syncthreads();
    for (int i = threadIdx.x; i < ce; i += 256)
        atomicAdd(&h[dst[beg + i] >> BKT_LG], 1);
    __syncthreads();
    for (int i = threadIdx.x; i < NB; i += 256) {
        res[i] = h[i] ? atomicAdd(&bfill[i], h[i]) : 0;
        h[i] = 0;
    }
    __syncthreads();
    for (int i = threadIdx.x; i < ce; i += 256) {
        int d = dst[beg + i];
        int b = d >> BKT_LG;
        int p = res[b] + atomicAdd(&h[b], 1);
        binned[p] = ((unsigned)src[beg + i] << BKT_LG) | (unsigned)(d & (BKT_SZ - 1));
    }
}

// ---- per-bucket: count per node, scan, emit rowptr/dinv, group col
__launch_bounds__(256)
static __global__ void group_kernel(const unsigned* __restrict__ binned, const int* __restrict__ base,
                                    int* __restrict__ rowptr, int* __restrict__ col,
                                    float* __restrict__ dinv, int N, int E) {
    __shared__ int cnt[BKT_SZ];
    __shared__ int ex[BKT_SZ];
    __shared__ int ps[256];
    const int tid = threadIdx.x;
    const int b = blockIdx.x;
    const int node0 = b << BKT_LG;
    const int nn = min(BKT_SZ, N - node0);
    const int beg = base[b], end = base[b + 1];

    for (int i = tid; i < BKT_SZ; i += 256) cnt[i] = 0;
    __syncthreads();
    for (int i = beg + tid; i < end; i += 256)
        atomicAdd(&cnt[binned[i] & (BKT_SZ - 1)], 1);
    __syncthreads();

    const int b4 = tid * 4;
    int c0 = cnt[b4], c1 = cnt[b4 + 1], c2 = cnt[b4 + 2], c3 = cnt[b4 + 3];
    int s01 = c0 + c1;
    int s = s01 + c2 + c3;
    ps[tid] = s;
    __syncthreads();
    for (int off = 1; off < 256; off <<= 1) {
        int u = (tid >= off) ? ps[tid - off] : 0;
        __syncthreads();
        ps[tid] += u;
        __syncthreads();
    }
    int excl = ps[tid] - s;
    ex[b4]     = excl;
    ex[b4 + 1] = excl + c0;
    ex[b4 + 2] = excl + s01;
    ex[b4 + 3] = excl + s01 + c2;
    __syncthreads();

    for (int i = tid; i < nn; i += 256) {
        rowptr[node0 + i] = beg + ex[i];
        dinv[node0 + i] = rsqrtf((float)cnt[i] + 1.0f);
    }
    if (b == 0 && tid == 0) rowptr[N] = E;
    __syncthreads();

    for (int i = beg + tid; i < end; i += 256) {
        unsigned v = binned[i];
        int dl = v & (BKT_SZ - 1);
        int p = atomicAdd(&ex[dl], 1);
        col[beg + p] = (int)(v >> BKT_LG);
    }
}

// o[row] = (half) x[row] * dinv[row], dim 64
static __global__ void scale_kernel(const float* __restrict__ x, const float* __restrict__ dinv,
                                    __half* __restrict__ o, int N) {
    int t = blockIdx.x * 256 + threadIdx.x;
    if (t >= N * 16) return;
    int row = t >> 4;
    int c = (t & 15) * 4;
    float d = dinv[row];
    float4 v = *(const float4*)&x[(size_t)row * 64 + c];
    v.x *= d; v.y *= d; v.z *= d; v.w *= d;
    f4toh4(&o[(size_t)row * 64 + c], v);
}

// gather one 64-dim fp16 node row slice for this lane (16-lane group), with
// dinv scale [+gbias relu]. fp32 accumulation. Sets dv.
template <bool GBR>
__device__ __forceinline__ float4 gather64(const __half* __restrict__ hs,
                                           const int* __restrict__ rowptr,
                                           const int* __restrict__ col,
                                           const float* __restrict__ dinv,
                                           const float* __restrict__ gbias,
                                           int node, int lane, float& dv) {
    constexpr int K = 64;
    const int beg = rowptr[node];
    const int end = rowptr[node + 1];
    float4 acc = h4tof4(&hs[(size_t)node * K + lane * 4]);  // self loop
    float4 acc2 = make_float4(0.f, 0.f, 0.f, 0.f);
    int e = beg;
    for (; e + 8 <= end; e += 8) {
        int myc = col[e + (lane & 7)];
        float4 v[8];
#pragma unroll
        for (int j = 0; j < 8; ++j) {
            int s = __shfl(myc, j, 16);
            v[j] = h4tof4(&hs[(size_t)s * K + lane * 4]);
        }
        f4add(acc, v[0]); f4add(acc2, v[1]);
        f4add(acc, v[2]); f4add(acc2, v[3]);
        f4add(acc, v[4]); f4add(acc2, v[5]);
        f4add(acc, v[6]); f4add(acc2, v[7]);
    }
    {
        const int m = end - e;  // 0..7
        int myc = (e + (lane & 7) < end) ? col[e + (lane & 7)] : 0;
#pragma unroll
        for (int j = 0; j < 7; ++j) {
            if (j < m) {
                int s = __shfl(myc, j, 16);
                float4 vv = h4tof4(&hs[(size_t)s * K + lane * 4]);
                f4add(acc, vv);
            }
        }
    }
    f4add(acc, acc2);
    dv = dinv[node];
    float4 r;
    r.x = acc.x * dv; r.y = acc.y * dv; r.z = acc.z * dv; r.w = acc.w * dv;
    if (GBR) {
        float4 bv = *(const float4*)&gbias[lane * 4];
        r.x = fmaxf(r.x + bv.x, 0.f);
        r.y = fmaxf(r.y + bv.y, 0.f);
        r.z = fmaxf(r.z + bv.z, 0.f);
        r.w = fmaxf(r.w + bv.w, 0.f);
    }
    return r;
}

// Fused gather(64,fp16) + fp16-packed GEMM(64->OUT), 1 node per 16-lane group.
// W staged in LDS as half2 pairs (consecutive k); dot via v_dot2_f32_f16
// (fp32 accum). GMODE 0: relu(acc+obias)->fp16 ; GMODE 1: acc*dinv->fp16.
template <int OUT, int NPB, bool GBR, int GMODE>
__launch_bounds__(NPB * 16)
static __global__ void fg_kernel(const __half* __restrict__ hs, const int* __restrict__ rowptr,
                                 const int* __restrict__ col, const float* __restrict__ dinv,
                                 const float* __restrict__ gbias, const float* __restrict__ W,
                                 const float* __restrict__ obias, __half* __restrict__ out, int N) {
    constexpr int K = 64;
    constexpr int NT = NPB * 16;
    constexpr int CPT = OUT / 16;          // 8 / 4 / 2
    __shared__ int Wl2[(K / 2) * OUT];     // half2-packed: (k,k+1) x col
    const int tid = threadIdx.x;

    for (int i = tid; i < (K / 2) * OUT; i += NT) {
        int c = i % OUT;
        int kk2 = i / OUT;
        Wl2[i] = pk2i(W[(size_t)(2 * kk2) * OUT + c], W[(size_t)(2 * kk2 + 1) * OUT + c]);
    }
    __syncthreads();   // only barrier: W resident

    const int lane = tid & 15;
    const int node = blockIdx.x * NPB + (tid >> 4);
    if (node >= N) return;

    float dv;
    float4 r = gather64<GBR>(hs, rowptr, col, dinv, gbias, node, lane, dv);

    // pack this lane's 4 agg values into two half2 (k pairs 2*lane, 2*lane+1)
    int ip0 = pk2i(r.x, r.y);
    int ip1 = pk2i(r.z, r.w);

    float oacc[CPT];
#pragma unroll
    for (int c = 0; c < CPT; ++c) oacc[c] = 0.f;

#pragma unroll
    for (int src = 0; src < 16; ++src) {
        half2v a0 = i2h(__shfl(ip0, src, 16));   // k pair 2*src
        half2v a1 = i2h(__shfl(ip1, src, 16));   // k pair 2*src+1
        if (CPT >= 4) {
#pragma unroll
            for (int c = 0; c < CPT / 4; ++c) {
                int4 w0 = *(int4*)&Wl2[(2 * src) * OUT + c * 64 + lane * 4];
                int4 w1 = *(int4*)&Wl2[(2 * src + 1) * OUT + c * 64 + lane * 4];
                oacc[c * 4 + 0] = FDOT2(a0, i2h(w0.x), oacc[c * 4 + 0]);
                oacc[c * 4 + 1] = FDOT2(a0, i2h(w0.y), oacc[c * 4 + 1]);
                oacc[c * 4 + 2] = FDOT2(a0, i2h(w0.z), oacc[c * 4 + 2]);
                oacc[c * 4 + 3] = FDOT2(a0, i2h(w0.w), oacc[c * 4 + 3]);
                oacc[c * 4 + 0] = FDOT2(a1, i2h(w1.x), oacc[c * 4 + 0]);
                oacc[c * 4 + 1] = FDOT2(a1, i2h(w1.y), oacc[c * 4 + 1]);
                oacc[c * 4 + 2] = FDOT2(a1, i2h(w1.z), oacc[c * 4 + 2]);
                oacc[c * 4 + 3] = FDOT2(a1, i2h(w1.w), oacc[c * 4 + 3]);
            }
        } else {
            int2 w0 = *(int2*)&Wl2[(2 * src) * OUT + lane * 2];
            int2 w1 = *(int2*)&Wl2[(2 * src + 1) * OUT + lane * 2];
            oacc[0] = FDOT2(a0, i2h(w0.x), oacc[0]);
            oacc[1] = FDOT2(a0, i2h(w0.y), oacc[1]);
            oacc[0] = FDOT2(a1, i2h(w1.x), oacc[0]);
            oacc[1] = FDOT2(a1, i2h(w1.y), oacc[1]);
        }
    }

    if (GMODE == 0) {
#pragma unroll
        for (int c = 0; c < CPT / 4; ++c) {
            float4 bv = *(const float4*)&obias[c * 64 + lane * 4];
            float4 o;
            o.x = fmaxf(oacc[c * 4 + 0] + bv.x, 0.f);
            o.y = fmaxf(oacc[c * 4 + 1] + bv.y, 0.f);
            o.z = fmaxf(oacc[c * 4 + 2] + bv.z, 0.f);
            o.w = fmaxf(oacc[c * 4 + 3] + bv.w, 0.f);
            f4toh4(&out[(size_t)node * OUT + c * 64 + lane * 4], o);
        }
    } else {
        if (CPT >= 4) {
#pragma unroll
            for (int c = 0; c < CPT / 4; ++c) {
                float4 o;
                o.x = oacc[c * 4 + 0] * dv;
                o.y = oacc[c * 4 + 1] * dv;
                o.z = oacc[c * 4 + 2] * dv;
                o.w = oacc[c * 4 + 3] * dv;
                f4toh4(&out[(size_t)node * OUT + c * 64 + lane * 4], o);
            }
        } else {
            *(__half2*)&out[(size_t)node * OUT + lane * 2] =
                __floats2half2_rn(oacc[0] * dv, oacc[1] * dv);
        }
    }
}

// Fused gather(32,fp16) + b4/relu + dot(Wfc) + segment-mean pooling.
__launch_bounds__(256)
static __global__ void fg4_kernel(const __half* __restrict__ hs, const int* __restrict__ rowptr,
                                  const int* __restrict__ col, const float* __restrict__ dinv,
                                  const float* __restrict__ b4, const float* __restrict__ Wfc,
                                  const int* __restrict__ batch, float* __restrict__ psum,
                                  int* __restrict__ pcnt, int N) {
    constexpr int K = 32;
    __shared__ float wl[32];
    __shared__ float gsum[64];
    __shared__ int gcnt[64];
    __shared__ int sbase;
    const int tid = threadIdx.x;
    if (tid < 32) wl[tid] = Wfc[tid];
    if (tid < 64) { gsum[tid] = 0.f; gcnt[tid] = 0; }
    if (tid == 0) {
        int bi = (int)blockIdx.x * 32;
        if (bi > N - 1) bi = N - 1;
        sbase = batch[bi];
    }
    __syncthreads();

    const int lane = tid & 7;
    const int li = tid >> 3;
    const int node = blockIdx.x * 32 + li;
    float val = 0.f;
    if (node < N) {
        const int beg = rowptr[node];
        const int end = rowptr[node + 1];
        float4 acc = h4tof4(&hs[(size_t)node * K + lane * 4]);
        float4 acc2 = make_float4(0.f, 0.f, 0.f, 0.f);
        int e = beg;
        for (; e + 8 <= end; e += 8) {
            int myc = col[e + lane];
            float4 v[8];
#pragma unroll
            for (int j = 0; j < 8; ++j) {
                int s = __shfl(myc, j, 8);
                v[j] = h4tof4(&hs[(size_t)s * K + lane * 4]);
            }
            f4add(acc, v[0]); f4add(acc2, v[1]);
            f4add(acc, v[2]); f4add(acc2, v[3]);
            f4add(acc, v[4]); f4add(acc2, v[5]);
            f4add(acc, v[6]); f4add(acc2, v[7]);
        }
        {
            const int m = end - e;
            int myc = (e + lane < end) ? col[e + lane] : 0;
#pragma unroll
            for (int j = 0; j < 7; ++j) {
                if (j < m) {
                    int s = __shfl(myc, j, 8);
                    float4 vv = h4tof4(&hs[(size_t)s * K + lane * 4]);
                    f4add(acc, vv);
                }
            }
        }
        f4add(acc, acc2);
        float dv = dinv[node];
        float4 bv = *(const float4*)&b4[lane * 4];
        float4 h;
        h.x = fmaxf(acc.x * dv + bv.x, 0.f);
        h.y = fmaxf(acc.y * dv + bv.y, 0.f);
        h.z = fmaxf(acc.z * dv + bv.z, 0.f);
        h.w = fmaxf(acc.w * dv + bv.w, 0.f);
        val = h.x * wl[lane * 4 + 0] + h.y * wl[lane * 4 + 1] +
              h.z * wl[lane * 4 + 2] + h.w * wl[lane * 4 + 3];
    }
    val += __shfl_xor(val, 1, 8);
    val += __shfl_xor(val, 2, 8);
    val += __shfl_xor(val, 4, 8);
    if (node < N && lane == 0) {
        int g = batch[node];
        int rel = g - sbase;
        if ((unsigned)rel < 64u) {
            atomicAdd(&gsum[rel], val);
            atomicAdd(&gcnt[rel], 1);
        } else {
            unsafeAtomicAdd(&psum[g], val);
            atomicAdd(&pcnt[g], 1);
        }
    }
    __syncthreads();
    if (tid < 64 && gcnt[tid] > 0) {
        unsafeAtomicAdd(&psum[sbase + tid], gsum[tid]);
        atomicAdd(&pcnt[sbase + tid], gcnt[tid]);
    }
}

// out(fp16) = Xin(fp16) @ W(fp32) * dinv[row]. W in LDS. (gemm2 only)
template <int K, int OUT, int RT>
__launch_bounds__(256)
static __global__ void gemm_kernel(const __half* __restrict__ Xin, const float* __restrict__ W,
                                   const float* __restrict__ dinv, __half* __restrict__ out, int N) {
    constexpr int CT = OUT / 4;
    constexpr int RTH = 256 / CT;
    constexpr int RB = RTH * RT;
    constexpr int KP = K + 4;
    __shared__ float Wl[K * OUT];
    __shared__ float Xl[RB * KP];

    const int tid = threadIdx.x;
    const int row0 = blockIdx.x * RB;

    for (int idx = tid; idx < K * OUT / 4; idx += 256)
        ((float4*)Wl)[idx] = ((const float4*)W)[idx];

    constexpr int KC = K / 4;
    for (int idx = tid; idx < RB * KC; idx += 256) {
        int r = idx / KC;
        int kc = idx - r * KC;
        int g = row0 + r;
        float4 v = (g < N) ? h4tof4(&Xin[(size_t)g * K + kc * 4])
                           : make_float4(0.f, 0.f, 0.f, 0.f);
        *(float4*)&Xl[r * KP + kc * 4] = v;
    }
    __syncthreads();

    const int tx = tid % CT, ty = tid / CT;
    const int col0 = tx * 4;
    float4 acc[RT];
#pragma unroll
    for (int i = 0; i < RT; i++) acc[i] = make_float4(0.f, 0.f, 0.f, 0.f);

#pragma unroll 4
    for (int k = 0; k < K; k += 4) {
        float4 w0 = *(float4*)&Wl[(k + 0) * OUT + col0];
        float4 w1 = *(float4*)&Wl[(k + 1) * OUT + col0];
        float4 w2 = *(float4*)&Wl[(k + 2) * OUT + col0];
        float4 w3 = *(float4*)&Wl[(k + 3) * OUT + col0];
#pragma unroll
        for (int i = 0; i < RT; i++) {
            float4 xv = *(float4*)&Xl[(ty * RT + i) * KP + k];
            acc[i].x += xv.x * w0.x + xv.y * w1.x + xv.z * w2.x + xv.w * w3.x;
            acc[i].y += xv.x * w0.y + xv.y * w1.y + xv.z * w2.y + xv.w * w3.y;
            acc[i].z += xv.x * w0.z + xv.y * w1.z + xv.z * w2.z + xv.w * w3.z;
            acc[i].w += xv.x * w0.w + xv.y * w1.w + xv.z * w2.w + xv.w * w3.w;
        }
    }

#pragma unroll
    for (int i = 0; i < RT; i++) {
        int g = row0 + ty * RT + i;
        if (g < N) {
            float d = dinv[g];
            float4 r;
            r.x = acc[i].x * d; r.y = acc[i].y * d;
            r.z = acc[i].z * d; r.w = acc[i].w * d;
            f4toh4(&out[(size_t)g * OUT + col0], r);
        }
    }
}

static __global__ void final_kernel(const float* __restrict__ psum, const int* __restrict__ pcnt,
                                    const float* __restrict__ bfc, float* __restrict__ out, int G) {
    int t = threadIdx.x;
    if (t < G) {
        float c = (float)pcnt[t];
        out[t] = psum[t] / fmaxf(c, 1.f) + bfc[0];
    }
}

extern "C" void kernel_launch(void* const* d_in, const int* in_sizes, int n_in,
                              void* d_out, int out_size, void* d_ws, size_t ws_size,
                              hipStream_t stream) {
    const float* x    = (const float*)d_in[0];
    const int*   ei   = (const int*)d_in[1];
    const int*   batch= (const int*)d_in[2];
    const float* W1   = (const float*)d_in[4];
    const float* b1   = (const float*)d_in[5];
    const float* W2   = (const float*)d_in[6];
    const float* b2   = (const float*)d_in[7];
    const float* W3   = (const float*)d_in[8];
    const float* b3   = (const float*)d_in[9];
    const float* W4   = (const float*)d_in[10];
    const float* b4   = (const float*)d_in[11];
    const float* Wfc  = (const float*)d_in[12];
    const float* bfc  = (const float*)d_in[13];
    float* out = (float*)d_out;

    const int N = in_sizes[0] / 64;
    const int E = in_sizes[1] / 2;
    const int G = out_size;
    const int* srcp = ei;
    const int* dstp = ei + E;
    const int NB = (N + BKT_SZ - 1) >> BKT_LG;   // 98 for N=100k

    // workspace layout (float-sized slots)
    float* wsf = (float*)d_ws;
    const size_t Npad = ((size_t)N + 1023) / 1024 * 1024;
    const size_t Epad = ((size_t)E + 1023) / 1024 * 1024;
    float*    dinv   = wsf;                            // Npad
    int*      rowptr = (int*)(wsf + Npad);             // Npad + 1024
    int*      col    = (int*)(wsf + 2 * Npad + 1024);  // Epad
    unsigned* binned = (unsigned*)((float*)col + Epad);// Epad
    int*      bcnt   = (int*)((float*)binned + Epad);  // 256
    int*      base   = bcnt + 256;                     // 256
    int*      bfill  = base + 256;                     // 256
    float*    psum   = (float*)(bfill + 256);          // 256
    int*      pcnt   = (int*)(psum + 256);             // 256
    __half*   T1h    = (__half*)(psum + 1024);         // Npad*64 halves
    __half*   T2h    = (__half*)((float*)T1h + Npad * 32); // Npad*64 halves
    __half*   H1h    = (__half*)((float*)T2h + Npad * 32); // Npad*128 halves

    const int gN   = (N + 255) / 256;
    const int gN16 = (N * 16 + 255) / 256;
    const int nbin = (E + BIN_CHUNK - 1) / BIN_CHUNK;
    const int gFG1 = (N + 31) / 32;   // 512 threads, 32 nodes
    const int gFG  = (N + 15) / 16;   // 256 threads, 16 nodes
    const int gFG4 = (N + 31) / 32;

    hipMemsetAsync(bcnt, 0, 256 * sizeof(int), stream);
    hipMemsetAsync(psum, 0, 512 * sizeof(float), stream);

    // ---- CSR build (by dst, col = src) + dinv
    bhist_kernel<<<256, 256, 0, stream>>>(dstp, bcnt, E, NB);
    bscan_kernel<<<1, 128, 0, stream>>>(bcnt, base, bfill, NB, E);
    bin_kernel<<<nbin, 256, 0, stream>>>(srcp, dstp, bfill, binned, E, NB);
    group_kernel<<<NB, 256, 0, stream>>>(binned, base, rowptr, col, dinv, N, E);

    // ---- layer 1: scale(fp16), fused gather+GEMM(64->128,+b1,relu) -> H1(fp16)
    scale_kernel<<<gN16, 256, 0, stream>>>(x, dinv, T1h, N);
    fg_kernel<128, 32, false, 0><<<gFG1, 512, 0, stream>>>(T1h, rowptr, col, dinv, nullptr, W1, b1, H1h, N);

    // ---- layer 2 GEMM: T2h = (H1h @ W2) * dinv  (fp16 out)
    gemm_kernel<128, 64, 2><<<(N + 31) / 32, 256, 0, stream>>>(H1h, W2, dinv, T2h, N);

    // ---- fused gather2(+b2,relu) + GEMM3(64->64, *dinv) -> T1h
    fg_kernel<64, 16, true, 1><<<gFG, 256, 0, stream>>>(T2h, rowptr, col, dinv, b2, W3, nullptr, T1h, N);

    // ---- fused gather3(+b3,relu) + GEMM4(64->32, *dinv) -> T2h (32-dim)
    fg_kernel<32, 16, true, 1><<<gFG, 256, 0, stream>>>(T1h, rowptr, col, dinv, b3, W4, nullptr, T2h, N);

    // ---- fused gather4(+b4,relu) + fc-dot + pooled segment sums
    fg4_kernel<<<gFG4, 256, 0, stream>>>(T2h, rowptr, col, dinv, b4, Wfc, batch, psum, pcnt, N);

    // ---- final mean + bias
    final_kernel<<<1, 256, 0, stream>>>(psum, pcnt, bfc, out, G);
}

// Round 16
// 374.646 us; speedup vs baseline: 3.1003x; 1.0137x over previous
//
#include <hip/hip_runtime.h>
#include <hip/hip_fp16.h>
#include <cstdint>
#include <cstddef>

// ---------------------------------------------------------------------------
// GCN regression. Round 16: packed-fp16 gather accumulation.
//   R15: FG kernels still issue-bound in the gather phase (16 cvt + 32 add
//   per 8-edge chunk). Now accumulate with v_pk_add_f16 (__hadd2): 2 inst
//   per edge, dual accumulator pairs (short rounding chains), single fp32
//   conversion at the end. GEMM phase unchanged (packed half2 W + fdot2).
//   Fallback if absmax > 8e-4: revert gather accum to fp32.
// ---------------------------------------------------------------------------

#define BKT_LG 10
#define BKT_SZ 1024
#define BIN_CHUNK 2048

using half2v = decltype(__builtin_amdgcn_cvt_pkrtz(0.0f, 0.0f));

#if __has_builtin(__builtin_amdgcn_fdot2)
#define FDOT2(a, b, c) __builtin_amdgcn_fdot2((a), (b), (c), false)
#else
__device__ __forceinline__ float fdot2_emul(half2v a, half2v b, float c) {
    return c + (float)a[0] * (float)b[0] + (float)a[1] * (float)b[1];
}
#define FDOT2(a, b, c) fdot2_emul((a), (b), (c))
#endif

__device__ __forceinline__ half2v i2h(int i) { union { int i; half2v h; } u; u.i = i; return u.h; }
__device__ __forceinline__ int h2i(half2v h) { union { int i; half2v h; } u; u.h = h; return u.i; }
__device__ __forceinline__ int pk2i(float a, float b) { return h2i(__builtin_amdgcn_cvt_pkrtz(a, b)); }

__device__ __forceinline__ float4 h4tof4(const __half* p) {
    union { uint2 u; __half2 h[2]; } cv;
    cv.u = *(const uint2*)p;
    float2 a = __half22float2(cv.h[0]);
    float2 b = __half22float2(cv.h[1]);
    return make_float4(a.x, a.y, b.x, b.y);
}
__device__ __forceinline__ void f4toh4(__half* p, float4 v) {
    union { uint2 u; __half2 h[2]; } cv;
    cv.h[0] = __floats2half2_rn(v.x, v.y);
    cv.h[1] = __floats2half2_rn(v.z, v.w);
    *(uint2*)p = cv.u;
}

// ---- bucket histogram
static __global__ void bhist_kernel(const int* __restrict__ dst, int* __restrict__ bcnt,
                                    int E, int NB) {
    __shared__ int h[128];
    for (int i = threadIdx.x; i < NB; i += 256) h[i] = 0;
    __syncthreads();
    for (int t = blockIdx.x * 256 + threadIdx.x; t < E; t += gridDim.x * 256)
        atomicAdd(&h[dst[t] >> BKT_LG], 1);
    __syncthreads();
    for (int i = threadIdx.x; i < NB; i += 256)
        if (h[i]) atomicAdd(&bcnt[i], h[i]);
}

// ---- exclusive scan of bcnt -> base (NB+1), bfill = base
static __global__ void bscan_kernel(const int* __restrict__ bcnt, int* __restrict__ base,
                                    int* __restrict__ bfill, int NB, int E) {
    __shared__ int s[128];
    int t = threadIdx.x;
    int v = (t < NB) ? bcnt[t] : 0;
    s[t] = v;
    __syncthreads();
    for (int off = 1; off < 128; off <<= 1) {
        int u = (t >= off) ? s[t - off] : 0;
        __syncthreads();
        s[t] += u;
        __syncthreads();
    }
    if (t < NB) { base[t] = s[t] - v; bfill[t] = s[t] - v; }
    if (t == 0) base[NB] = E;
}

// ---- bin edges into bucket-contiguous runs
__launch_bounds__(256)
static __global__ void bin_kernel(const int* __restrict__ src, const int* __restrict__ dst,
                                  int* __restrict__ bfill, unsigned* __restrict__ binned,
                                  int E, int NB) {
    __shared__ int h[128];
    __shared__ int res[128];
    const int beg = blockIdx.x * BIN_CHUNK;
    const int ce = min(BIN_CHUNK, E - beg);
    for (int i = threadIdx.x; i < NB; i += 256) h[i] = 0;
    __syncthreads();
    for (int i = threadIdx.x; i < ce; i += 256)
        atomicAdd(&h[dst[beg + i] >> BKT_LG], 1);
    __syncthreads();
    for (int i = threadIdx.x; i < NB; i += 256) {
        res[i] = h[i] ? atomicAdd(&bfill[i], h[i]) : 0;
        h[i] = 0;
    }
    __syncthreads();
    for (int i = threadIdx.x; i < ce; i += 256) {
        int d = dst[beg + i];
        int b = d >> BKT_LG;
        int p = res[b] + atomicAdd(&h[b], 1);
        binned[p] = ((unsigned)src[beg + i] << BKT_LG) | (unsigned)(d & (BKT_SZ - 1));
    }
}

// ---- per-bucket: count per node, scan, emit rowptr/dinv, group col
__launch_bounds__(256)
static __global__ void group_kernel(const unsigned* __restrict__ binned, const int* __restrict__ base,
                                    int* __restrict__ rowptr, int* __restrict__ col,
                                    float* __restrict__ dinv, int N, int E) {
    __shared__ int cnt[BKT_SZ];
    __shared__ int ex[BKT_SZ];
    __shared__ int ps[256];
    const int tid = threadIdx.x;
    const int b = blockIdx.x;
    const int node0 = b << BKT_LG;
    const int nn = min(BKT_SZ, N - node0);
    const int beg = base[b], end = base[b + 1];

    for (int i = tid; i < BKT_SZ; i += 256) cnt[i] = 0;
    __syncthreads();
    for (int i = beg + tid; i < end; i += 256)
        atomicAdd(&cnt[binned[i] & (BKT_SZ - 1)], 1);
    __syncthreads();

    const int b4 = tid * 4;
    int c0 = cnt[b4], c1 = cnt[b4 + 1], c2 = cnt[b4 + 2], c3 = cnt[b4 + 3];
    int s01 = c0 + c1;
    int s = s01 + c2 + c3;
    ps[tid] = s;
    __syncthreads();
    for (int off = 1; off < 256; off <<= 1) {
        int u = (tid >= off) ? ps[tid - off] : 0;
        __syncthreads();
        ps[tid] += u;
        __syncthreads();
    }
    int excl = ps[tid] - s;
    ex[b4]     = excl;
    ex[b4 + 1] = excl + c0;
    ex[b4 + 2] = excl + s01;
    ex[b4 + 3] = excl + s01 + c2;
    __syncthreads();

    for (int i = tid; i < nn; i += 256) {
        rowptr[node0 + i] = beg + ex[i];
        dinv[node0 + i] = rsqrtf((float)cnt[i] + 1.0f);
    }
    if (b == 0 && tid == 0) rowptr[N] = E;
    __syncthreads();

    for (int i = beg + tid; i < end; i += 256) {
        unsigned v = binned[i];
        int dl = v & (BKT_SZ - 1);
        int p = atomicAdd(&ex[dl], 1);
        col[beg + p] = (int)(v >> BKT_LG);
    }
}

// o[row] = (half) x[row] * dinv[row], dim 64
static __global__ void scale_kernel(const float* __restrict__ x, const float* __restrict__ dinv,
                                    __half* __restrict__ o, int N) {
    int t = blockIdx.x * 256 + threadIdx.x;
    if (t >= N * 16) return;
    int row = t >> 4;
    int c = (t & 15) * 4;
    float d = dinv[row];
    float4 v = *(const float4*)&x[(size_t)row * 64 + c];
    v.x *= d; v.y *= d; v.z *= d; v.w *= d;
    f4toh4(&o[(size_t)row * 64 + c], v);
}

// gather one 64-dim fp16 node row slice for this lane (16-lane group).
// Packed-fp16 accumulation (v_pk_add_f16), dual accumulator pairs, fp32
// combine at the end; dinv scale [+gbias relu]. Sets dv.
template <bool GBR>
__device__ __forceinline__ float4 gather64(const __half* __restrict__ hs,
                                           const int* __restrict__ rowptr,
                                           const int* __restrict__ col,
                                           const float* __restrict__ dinv,
                                           const float* __restrict__ gbias,
                                           int node, int lane, float& dv) {
    constexpr int K = 64;
    const int beg = rowptr[node];
    const int end = rowptr[node + 1];
    union { uint2 u; __half2 h[2]; } cv;
    cv.u = *(const uint2*)&hs[(size_t)node * K + lane * 4];   // self loop
    __half2 a0 = cv.h[0], a1 = cv.h[1];
    __half2 b0 = __float2half2_rn(0.f), b1 = __float2half2_rn(0.f);
    int e = beg;
    for (; e + 8 <= end; e += 8) {
        int myc = col[e + (lane & 7)];
        uint2 v[8];
#pragma unroll
        for (int j = 0; j < 8; ++j) {
            int s = __shfl(myc, j, 16);
            v[j] = *(const uint2*)&hs[(size_t)s * K + lane * 4];
        }
#pragma unroll
        for (int j = 0; j < 8; j += 2) {
            union { uint2 u; __half2 h[2]; } c0, c1;
            c0.u = v[j]; c1.u = v[j + 1];
            a0 = __hadd2(a0, c0.h[0]); a1 = __hadd2(a1, c0.h[1]);
            b0 = __hadd2(b0, c1.h[0]); b1 = __hadd2(b1, c1.h[1]);
        }
    }
    {
        const int m = end - e;  // 0..7
        int myc = (e + (lane & 7) < end) ? col[e + (lane & 7)] : 0;
#pragma unroll
        for (int j = 0; j < 7; ++j) {
            if (j < m) {
                int s = __shfl(myc, j, 16);
                union { uint2 u; __half2 h[2]; } c0;
                c0.u = *(const uint2*)&hs[(size_t)s * K + lane * 4];
                a0 = __hadd2(a0, c0.h[0]); a1 = __hadd2(a1, c0.h[1]);
            }
        }
    }
    // fp32 combine of the two accumulator pairs
    float2 fa0 = __half22float2(a0), fa1 = __half22float2(a1);
    float2 fb0 = __half22float2(b0), fb1 = __half22float2(b1);
    dv = dinv[node];
    float4 r;
    r.x = (fa0.x + fb0.x) * dv;
    r.y = (fa0.y + fb0.y) * dv;
    r.z = (fa1.x + fb1.x) * dv;
    r.w = (fa1.y + fb1.y) * dv;
    if (GBR) {
        float4 bv = *(const float4*)&gbias[lane * 4];
        r.x = fmaxf(r.x + bv.x, 0.f);
        r.y = fmaxf(r.y + bv.y, 0.f);
        r.z = fmaxf(r.z + bv.z, 0.f);
        r.w = fmaxf(r.w + bv.w, 0.f);
    }
    return r;
}

// Fused gather(64,fp16) + fp16-packed GEMM(64->OUT), 1 node per 16-lane group.
// W staged in LDS as half2 pairs; dot via v_dot2_f32_f16 (fp32 accum).
// GMODE 0: relu(acc+obias)->fp16 ; GMODE 1: acc*dinv->fp16.
template <int OUT, int NPB, bool GBR, int GMODE>
__launch_bounds__(NPB * 16)
static __global__ void fg_kernel(const __half* __restrict__ hs, const int* __restrict__ rowptr,
                                 const int* __restrict__ col, const float* __restrict__ dinv,
                                 const float* __restrict__ gbias, const float* __restrict__ W,
                                 const float* __restrict__ obias, __half* __restrict__ out, int N) {
    constexpr int K = 64;
    constexpr int NT = NPB * 16;
    constexpr int CPT = OUT / 16;          // 8 / 4 / 2
    __shared__ int Wl2[(K / 2) * OUT];     // half2-packed: (k,k+1) x col
    const int tid = threadIdx.x;

    for (int i = tid; i < (K / 2) * OUT; i += NT) {
        int c = i % OUT;
        int kk2 = i / OUT;
        Wl2[i] = pk2i(W[(size_t)(2 * kk2) * OUT + c], W[(size_t)(2 * kk2 + 1) * OUT + c]);
    }
    __syncthreads();   // only barrier: W resident

    const int lane = tid & 15;
    const int node = blockIdx.x * NPB + (tid >> 4);
    if (node >= N) return;

    float dv;
    float4 r = gather64<GBR>(hs, rowptr, col, dinv, gbias, node, lane, dv);

    // pack this lane's 4 agg values into two half2 (k pairs 2*lane, 2*lane+1)
    int ip0 = pk2i(r.x, r.y);
    int ip1 = pk2i(r.z, r.w);

    float oacc[CPT];
#pragma unroll
    for (int c = 0; c < CPT; ++c) oacc[c] = 0.f;

#pragma unroll
    for (int src = 0; src < 16; ++src) {
        half2v a0 = i2h(__shfl(ip0, src, 16));   // k pair 2*src
        half2v a1 = i2h(__shfl(ip1, src, 16));   // k pair 2*src+1
        if (CPT >= 4) {
#pragma unroll
            for (int c = 0; c < CPT / 4; ++c) {
                int4 w0 = *(int4*)&Wl2[(2 * src) * OUT + c * 64 + lane * 4];
                int4 w1 = *(int4*)&Wl2[(2 * src + 1) * OUT + c * 64 + lane * 4];
                oacc[c * 4 + 0] = FDOT2(a0, i2h(w0.x), oacc[c * 4 + 0]);
                oacc[c * 4 + 1] = FDOT2(a0, i2h(w0.y), oacc[c * 4 + 1]);
                oacc[c * 4 + 2] = FDOT2(a0, i2h(w0.z), oacc[c * 4 + 2]);
                oacc[c * 4 + 3] = FDOT2(a0, i2h(w0.w), oacc[c * 4 + 3]);
                oacc[c * 4 + 0] = FDOT2(a1, i2h(w1.x), oacc[c * 4 + 0]);
                oacc[c * 4 + 1] = FDOT2(a1, i2h(w1.y), oacc[c * 4 + 1]);
                oacc[c * 4 + 2] = FDOT2(a1, i2h(w1.z), oacc[c * 4 + 2]);
                oacc[c * 4 + 3] = FDOT2(a1, i2h(w1.w), oacc[c * 4 + 3]);
            }
        } else {
            int2 w0 = *(int2*)&Wl2[(2 * src) * OUT + lane * 2];
            int2 w1 = *(int2*)&Wl2[(2 * src + 1) * OUT + lane * 2];
            oacc[0] = FDOT2(a0, i2h(w0.x), oacc[0]);
            oacc[1] = FDOT2(a0, i2h(w0.y), oacc[1]);
            oacc[0] = FDOT2(a1, i2h(w1.x), oacc[0]);
            oacc[1] = FDOT2(a1, i2h(w1.y), oacc[1]);
        }
    }

    if (GMODE == 0) {
#pragma unroll
        for (int c = 0; c < CPT / 4; ++c) {
            float4 bv = *(const float4*)&obias[c * 64 + lane * 4];
            float4 o;
            o.x = fmaxf(oacc[c * 4 + 0] + bv.x, 0.f);
            o.y = fmaxf(oacc[c * 4 + 1] + bv.y, 0.f);
            o.z = fmaxf(oacc[c * 4 + 2] + bv.z, 0.f);
            o.w = fmaxf(oacc[c * 4 + 3] + bv.w, 0.f);
            f4toh4(&out[(size_t)node * OUT + c * 64 + lane * 4], o);
        }
    } else {
        if (CPT >= 4) {
#pragma unroll
            for (int c = 0; c < CPT / 4; ++c) {
                float4 o;
                o.x = oacc[c * 4 + 0] * dv;
                o.y = oacc[c * 4 + 1] * dv;
                o.z = oacc[c * 4 + 2] * dv;
                o.w = oacc[c * 4 + 3] * dv;
                f4toh4(&out[(size_t)node * OUT + c * 64 + lane * 4], o);
            }
        } else {
            *(__half2*)&out[(size_t)node * OUT + lane * 2] =
                __floats2half2_rn(oacc[0] * dv, oacc[1] * dv);
        }
    }
}

// Fused gather(32,fp16) + b4/relu + dot(Wfc) + segment-mean pooling.
// Packed-fp16 gather accumulation as above.
__launch_bounds__(256)
static __global__ void fg4_kernel(const __half* __restrict__ hs, const int* __restrict__ rowptr,
                                  const int* __restrict__ col, const float* __restrict__ dinv,
                                  const float* __restrict__ b4, const float* __restrict__ Wfc,
                                  const int* __restrict__ batch, float* __restrict__ psum,
                                  int* __restrict__ pcnt, int N) {
    constexpr int K = 32;
    __shared__ float wl[32];
    __shared__ float gsum[64];
    __shared__ int gcnt[64];
    __shared__ int sbase;
    const int tid = threadIdx.x;
    if (tid < 32) wl[tid] = Wfc[tid];
    if (tid < 64) { gsum[tid] = 0.f; gcnt[tid] = 0; }
    if (tid == 0) {
        int bi = (int)blockIdx.x * 32;
        if (bi > N - 1) bi = N - 1;
        sbase = batch[bi];
    }
    __syncthreads();

    const int lane = tid & 7;
    const int li = tid >> 3;
    const int node = blockIdx.x * 32 + li;
    float val = 0.f;
    if (node < N) {
        const int beg = rowptr[node];
        const int end = rowptr[node + 1];
        union { uint2 u; __half2 h[2]; } cv;
        cv.u = *(const uint2*)&hs[(size_t)node * K + lane * 4];
        __half2 a0 = cv.h[0], a1 = cv.h[1];
        __half2 b0h = __float2half2_rn(0.f), b1h = __float2half2_rn(0.f);
        int e = beg;
        for (; e + 8 <= end; e += 8) {
            int myc = col[e + lane];
            uint2 v[8];
#pragma unroll
            for (int j = 0; j < 8; ++j) {
                int s = __shfl(myc, j, 8);
                v[j] = *(const uint2*)&hs[(size_t)s * K + lane * 4];
            }
#pragma unroll
            for (int j = 0; j < 8; j += 2) {
                union { uint2 u; __half2 h[2]; } c0, c1;
                c0.u = v[j]; c1.u = v[j + 1];
                a0 = __hadd2(a0, c0.h[0]); a1 = __hadd2(a1, c0.h[1]);
                b0h = __hadd2(b0h, c1.h[0]); b1h = __hadd2(b1h, c1.h[1]);
            }
        }
        {
            const int m = end - e;
            int myc = (e + lane < end) ? col[e + lane] : 0;
#pragma unroll
            for (int j = 0; j < 7; ++j) {
                if (j < m) {
                    int s = __shfl(myc, j, 8);
                    union { uint2 u; __half2 h[2]; } c0;
                    c0.u = *(const uint2*)&hs[(size_t)s * K + lane * 4];
                    a0 = __hadd2(a0, c0.h[0]); a1 = __hadd2(a1, c0.h[1]);
                }
            }
        }
        float2 fa0 = __half22float2(a0), fa1 = __half22float2(a1);
        float2 fb0 = __half22float2(b0h), fb1 = __half22float2(b1h);
        float dv = dinv[node];
        float4 bv = *(const float4*)&b4[lane * 4];
        float4 h;
        h.x = fmaxf((fa0.x + fb0.x) * dv + bv.x, 0.f);
        h.y = fmaxf((fa0.y + fb0.y) * dv + bv.y, 0.f);
        h.z = fmaxf((fa1.x + fb1.x) * dv + bv.z, 0.f);
        h.w = fmaxf((fa1.y + fb1.y) * dv + bv.w, 0.f);
        val = h.x * wl[lane * 4 + 0] + h.y * wl[lane * 4 + 1] +
              h.z * wl[lane * 4 + 2] + h.w * wl[lane * 4 + 3];
    }
    val += __shfl_xor(val, 1, 8);
    val += __shfl_xor(val, 2, 8);
    val += __shfl_xor(val, 4, 8);
    if (node < N && lane == 0) {
        int g = batch[node];
        int rel = g - sbase;
        if ((unsigned)rel < 64u) {
            atomicAdd(&gsum[rel], val);
            atomicAdd(&gcnt[rel], 1);
        } else {
            unsafeAtomicAdd(&psum[g], val);
            atomicAdd(&pcnt[g], 1);
        }
    }
    __syncthreads();
    if (tid < 64 && gcnt[tid] > 0) {
        unsafeAtomicAdd(&psum[sbase + tid], gsum[tid]);
        atomicAdd(&pcnt[sbase + tid], gcnt[tid]);
    }
}

// out(fp16) = Xin(fp16) @ W(fp32) * dinv[row]. W in LDS. (gemm2 only)
template <int K, int OUT, int RT>
__launch_bounds__(256)
static __global__ void gemm_kernel(const __half* __restrict__ Xin, const float* __restrict__ W,
                                   const float* __restrict__ dinv, __half* __restrict__ out, int N) {
    constexpr int CT = OUT / 4;
    constexpr int RTH = 256 / CT;
    constexpr int RB = RTH * RT;
    constexpr int KP = K + 4;
    __shared__ float Wl[K * OUT];
    __shared__ float Xl[RB * KP];

    const int tid = threadIdx.x;
    const int row0 = blockIdx.x * RB;

    for (int idx = tid; idx < K * OUT / 4; idx += 256)
        ((float4*)Wl)[idx] = ((const float4*)W)[idx];

    constexpr int KC = K / 4;
    for (int idx = tid; idx < RB * KC; idx += 256) {
        int r = idx / KC;
        int kc = idx - r * KC;
        int g = row0 + r;
        float4 v = (g < N) ? h4tof4(&Xin[(size_t)g * K + kc * 4])
                           : make_float4(0.f, 0.f, 0.f, 0.f);
        *(float4*)&Xl[r * KP + kc * 4] = v;
    }
    __syncthreads();

    const int tx = tid % CT, ty = tid / CT;
    const int col0 = tx * 4;
    float4 acc[RT];
#pragma unroll
    for (int i = 0; i < RT; i++) acc[i] = make_float4(0.f, 0.f, 0.f, 0.f);

#pragma unroll 4
    for (int k = 0; k < K; k += 4) {
        float4 w0 = *(float4*)&Wl[(k + 0) * OUT + col0];
        float4 w1 = *(float4*)&Wl[(k + 1) * OUT + col0];
        float4 w2 = *(float4*)&Wl[(k + 2) * OUT + col0];
        float4 w3 = *(float4*)&Wl[(k + 3) * OUT + col0];
#pragma unroll
        for (int i = 0; i < RT; i++) {
            float4 xv = *(float4*)&Xl[(ty * RT + i) * KP + k];
            acc[i].x += xv.x * w0.x + xv.y * w1.x + xv.z * w2.x + xv.w * w3.x;
            acc[i].y += xv.x * w0.y + xv.y * w1.y + xv.z * w2.y + xv.w * w3.y;
            acc[i].z += xv.x * w0.z + xv.y * w1.z + xv.z * w2.z + xv.w * w3.z;
            acc[i].w += xv.x * w0.w + xv.y * w1.w + xv.z * w2.w + xv.w * w3.w;
        }
    }

#pragma unroll
    for (int i = 0; i < RT; i++) {
        int g = row0 + ty * RT + i;
        if (g < N) {
            float d = dinv[g];
            float4 r;
            r.x = acc[i].x * d; r.y = acc[i].y * d;
            r.z = acc[i].z * d; r.w = acc[i].w * d;
            f4toh4(&out[(size_t)g * OUT + col0], r);
        }
    }
}

static __global__ void final_kernel(const float* __restrict__ psum, const int* __restrict__ pcnt,
                                    const float* __restrict__ bfc, float* __restrict__ out, int G) {
    int t = threadIdx.x;
    if (t < G) {
        float c = (float)pcnt[t];
        out[t] = psum[t] / fmaxf(c, 1.f) + bfc[0];
    }
}

extern "C" void kernel_launch(void* const* d_in, const int* in_sizes, int n_in,
                              void* d_out, int out_size, void* d_ws, size_t ws_size,
                              hipStream_t stream) {
    const float* x    = (const float*)d_in[0];
    const int*   ei   = (const int*)d_in[1];
    const int*   batch= (const int*)d_in[2];
    const float* W1   = (const float*)d_in[4];
    const float* b1   = (const float*)d_in[5];
    const float* W2   = (const float*)d_in[6];
    const float* b2   = (const float*)d_in[7];
    const float* W3   = (const float*)d_in[8];
    const float* b3   = (const float*)d_in[9];
    const float* W4   = (const float*)d_in[10];
    const float* b4   = (const float*)d_in[11];
    const float* Wfc  = (const float*)d_in[12];
    const float* bfc  = (const float*)d_in[13];
    float* out = (float*)d_out;

    const int N = in_sizes[0] / 64;
    const int E = in_sizes[1] / 2;
    const int G = out_size;
    const int* srcp = ei;
    const int* dstp = ei + E;
    const int NB = (N + BKT_SZ - 1) >> BKT_LG;   // 98 for N=100k

    // workspace layout (float-sized slots)
    float* wsf = (float*)d_ws;
    const size_t Npad = ((size_t)N + 1023) / 1024 * 1024;
    const size_t Epad = ((size_t)E + 1023) / 1024 * 1024;
    float*    dinv   = wsf;                            // Npad
    int*      rowptr = (int*)(wsf + Npad);             // Npad + 1024
    int*      col    = (int*)(wsf + 2 * Npad + 1024);  // Epad
    unsigned* binned = (unsigned*)((float*)col + Epad);// Epad
    int*      bcnt   = (int*)((float*)binned + Epad);  // 256
    int*      base   = bcnt + 256;                     // 256
    int*      bfill  = base + 256;                     // 256
    float*    psum   = (float*)(bfill + 256);          // 256
    int*      pcnt   = (int*)(psum + 256);             // 256
    __half*   T1h    = (__half*)(psum + 1024);         // Npad*64 halves
    __half*   T2h    = (__half*)((float*)T1h + Npad * 32); // Npad*64 halves
    __half*   H1h    = (__half*)((float*)T2h + Npad * 32); // Npad*128 halves

    const int gN   = (N + 255) / 256;
    const int gN16 = (N * 16 + 255) / 256;
    const int nbin = (E + BIN_CHUNK - 1) / BIN_CHUNK;
    const int gFG1 = (N + 31) / 32;   // 512 threads, 32 nodes
    const int gFG  = (N + 15) / 16;   // 256 threads, 16 nodes
    const int gFG4 = (N + 31) / 32;

    hipMemsetAsync(bcnt, 0, 256 * sizeof(int), stream);
    hipMemsetAsync(psum, 0, 512 * sizeof(float), stream);

    // ---- CSR build (by dst, col = src) + dinv
    bhist_kernel<<<256, 256, 0, stream>>>(dstp, bcnt, E, NB);
    bscan_kernel<<<1, 128, 0, stream>>>(bcnt, base, bfill, NB, E);
    bin_kernel<<<nbin, 256, 0, stream>>>(srcp, dstp, bfill, binned, E, NB);
    group_kernel<<<NB, 256, 0, stream>>>(binned, base, rowptr, col, dinv, N, E);

    // ---- layer 1: scale(fp16), fused gather+GEMM(64->128,+b1,relu) -> H1(fp16)
    scale_kernel<<<gN16, 256, 0, stream>>>(x, dinv, T1h, N);
    fg_kernel<128, 32, false, 0><<<gFG1, 512, 0, stream>>>(T1h, rowptr, col, dinv, nullptr, W1, b1, H1h, N);

    // ---- layer 2 GEMM: T2h = (H1h @ W2) * dinv  (fp16 out)
    gemm_kernel<128, 64, 2><<<(N + 31) / 32, 256, 0, stream>>>(H1h, W2, dinv, T2h, N);

    // ---- fused gather2(+b2,relu) + GEMM3(64->64, *dinv) -> T1h
    fg_kernel<64, 16, true, 1><<<gFG, 256, 0, stream>>>(T2h, rowptr, col, dinv, b2, W3, nullptr, T1h, N);

    // ---- fused gather3(+b3,relu) + GEMM4(64->32, *dinv) -> T2h (32-dim)
    fg_kernel<32, 16, true, 1><<<gFG, 256, 0, stream>>>(T1h, rowptr, col, dinv, b3, W4, nullptr, T2h, N);

    // ---- fused gather4(+b4,relu) + fc-dot + pooled segment sums
    fg4_kernel<<<gFG4, 256, 0, stream>>>(T2h, rowptr, col, dinv, b4, Wfc, batch, psum, pcnt, N);

    // ---- final mean + bias
    final_kernel<<<1, 256, 0, stream>>>(psum, pcnt, bfc, out, G);
}

// Round 17
// 359.602 us; speedup vs baseline: 3.2300x; 1.0418x over previous
//
#include <hip/hip_runtime.h>
#include <hip/hip_fp16.h>
#include <cstdint>
#include <cstddef>

// ---------------------------------------------------------------------------
// GCN regression. Round 17: CSR-build parallelism retune.
//   R16 audit: fused gathers ~155us of 375; suspected ~100us in CSR build --
//   group_kernel ran only 98 blocks (1024-node buckets) on 256 CUs (same
//   under-parallelization that cost bin_kernel 70us in R3). Buckets 1024->256
//   (NB=391): group 4x blocks, bhist 782 strided blocks, bscan 512-wide.
//   FG path (fp16 storage, packed-fp16 gather accum + fdot2 GEMM) unchanged.
// ---------------------------------------------------------------------------

#define BKT_LG 8
#define BKT_SZ 256
#define BIN_CHUNK 2048

using half2v = decltype(__builtin_amdgcn_cvt_pkrtz(0.0f, 0.0f));

#if __has_builtin(__builtin_amdgcn_fdot2)
#define FDOT2(a, b, c) __builtin_amdgcn_fdot2((a), (b), (c), false)
#else
__device__ __forceinline__ float fdot2_emul(half2v a, half2v b, float c) {
    return c + (float)a[0] * (float)b[0] + (float)a[1] * (float)b[1];
}
#define FDOT2(a, b, c) fdot2_emul((a), (b), (c))
#endif

__device__ __forceinline__ half2v i2h(int i) { union { int i; half2v h; } u; u.i = i; return u.h; }
__device__ __forceinline__ int h2i(half2v h) { union { int i; half2v h; } u; u.h = h; return u.i; }
__device__ __forceinline__ int pk2i(float a, float b) { return h2i(__builtin_amdgcn_cvt_pkrtz(a, b)); }

__device__ __forceinline__ float4 h4tof4(const __half* p) {
    union { uint2 u; __half2 h[2]; } cv;
    cv.u = *(const uint2*)p;
    float2 a = __half22float2(cv.h[0]);
    float2 b = __half22float2(cv.h[1]);
    return make_float4(a.x, a.y, b.x, b.y);
}
__device__ __forceinline__ void f4toh4(__half* p, float4 v) {
    union { uint2 u; __half2 h[2]; } cv;
    cv.h[0] = __floats2half2_rn(v.x, v.y);
    cv.h[1] = __floats2half2_rn(v.z, v.w);
    *(uint2*)p = cv.u;
}

// ---- bucket histogram: bcnt[b] = #edges with dst in bucket b
static __global__ void bhist_kernel(const int* __restrict__ dst, int* __restrict__ bcnt,
                                    int E, int NB) {
    __shared__ int h[512];
    for (int i = threadIdx.x; i < NB; i += 256) h[i] = 0;
    __syncthreads();
    for (int t = blockIdx.x * 256 + threadIdx.x; t < E; t += gridDim.x * 256)
        atomicAdd(&h[dst[t] >> BKT_LG], 1);
    __syncthreads();
    for (int i = threadIdx.x; i < NB; i += 256)
        if (h[i]) atomicAdd(&bcnt[i], h[i]);
}

// ---- exclusive scan of bcnt -> base (NB+1), bfill = base  (single block, 512)
static __global__ void bscan_kernel(const int* __restrict__ bcnt, int* __restrict__ base,
                                    int* __restrict__ bfill, int NB, int E) {
    __shared__ int s[512];
    int t = threadIdx.x;
    int v = (t < NB) ? bcnt[t] : 0;
    s[t] = v;
    __syncthreads();
    for (int off = 1; off < 512; off <<= 1) {
        int u = (t >= off) ? s[t - off] : 0;
        __syncthreads();
        s[t] += u;
        __syncthreads();
    }
    if (t < NB) { base[t] = s[t] - v; bfill[t] = s[t] - v; }
    if (t == 0) base[NB] = E;
}

// ---- bin edges into bucket-contiguous runs
__launch_bounds__(256)
static __global__ void bin_kernel(const int* __restrict__ src, const int* __restrict__ dst,
                                  int* __restrict__ bfill, unsigned* __restrict__ binned,
                                  int E, int NB) {
    __shared__ int h[512];
    __shared__ int res[512];
    const int beg = blockIdx.x * BIN_CHUNK;
    const int ce = min(BIN_CHUNK, E - beg);
    for (int i = threadIdx.x; i < NB; i += 256) h[i] = 0;
    __syncthreads();
    for (int i = threadIdx.x; i < ce; i += 256)
        atomicAdd(&h[dst[beg + i] >> BKT_LG], 1);
    __syncthreads();
    for (int i = threadIdx.x; i < NB; i += 256) {
        res[i] = h[i] ? atomicAdd(&bfill[i], h[i]) : 0;
        h[i] = 0;
    }
    __syncthreads();
    for (int i = threadIdx.x; i < ce; i += 256) {
        int d = dst[beg + i];
        int b = d >> BKT_LG;
        int p = res[b] + atomicAdd(&h[b], 1);
        binned[p] = ((unsigned)src[beg + i] << BKT_LG) | (unsigned)(d & (BKT_SZ - 1));
    }
}

// ---- per-bucket (256 nodes): count, scan, emit rowptr/dinv, group col
__launch_bounds__(256)
static __global__ void group_kernel(const unsigned* __restrict__ binned, const int* __restrict__ base,
                                    int* __restrict__ rowptr, int* __restrict__ col,
                                    float* __restrict__ dinv, int N, int E) {
    __shared__ int cnt[BKT_SZ];
    __shared__ int ex[BKT_SZ];
    __shared__ int ps[256];
    const int tid = threadIdx.x;
    const int b = blockIdx.x;
    const int node0 = b << BKT_LG;
    const int nn = min(BKT_SZ, N - node0);
    const int beg = base[b], end = base[b + 1];

    cnt[tid] = 0;
    __syncthreads();
    for (int i = beg + tid; i < end; i += 256)
        atomicAdd(&cnt[binned[i] & (BKT_SZ - 1)], 1);
    __syncthreads();

    int c = cnt[tid];
    ps[tid] = c;
    __syncthreads();
    for (int off = 1; off < 256; off <<= 1) {
        int u = (tid >= off) ? ps[tid - off] : 0;
        __syncthreads();
        ps[tid] += u;
        __syncthreads();
    }
    int excl = ps[tid] - c;
    ex[tid] = excl;
    __syncthreads();

    if (tid < nn) {
        rowptr[node0 + tid] = beg + excl;
        dinv[node0 + tid] = rsqrtf((float)c + 1.0f);
    }
    if (b == 0 && tid == 0) rowptr[N] = E;
    __syncthreads();

    for (int i = beg + tid; i < end; i += 256) {
        unsigned v = binned[i];
        int dl = v & (BKT_SZ - 1);
        int p = atomicAdd(&ex[dl], 1);
        col[beg + p] = (int)(v >> BKT_LG);
    }
}

// o[row] = (half) x[row] * dinv[row], dim 64
static __global__ void scale_kernel(const float* __restrict__ x, const float* __restrict__ dinv,
                                    __half* __restrict__ o, int N) {
    int t = blockIdx.x * 256 + threadIdx.x;
    if (t >= N * 16) return;
    int row = t >> 4;
    int c = (t & 15) * 4;
    float d = dinv[row];
    float4 v = *(const float4*)&x[(size_t)row * 64 + c];
    v.x *= d; v.y *= d; v.z *= d; v.w *= d;
    f4toh4(&o[(size_t)row * 64 + c], v);
}

// gather one 64-dim fp16 node row slice for this lane (16-lane group).
// Packed-fp16 accumulation (v_pk_add_f16), dual accumulator pairs, fp32
// combine at the end; dinv scale [+gbias relu]. Sets dv.
template <bool GBR>
__device__ __forceinline__ float4 gather64(const __half* __restrict__ hs,
                                           const int* __restrict__ rowptr,
                                           const int* __restrict__ col,
                                           const float* __restrict__ dinv,
                                           const float* __restrict__ gbias,
                                           int node, int lane, float& dv) {
    constexpr int K = 64;
    const int beg = rowptr[node];
    const int end = rowptr[node + 1];
    union { uint2 u; __half2 h[2]; } cv;
    cv.u = *(const uint2*)&hs[(size_t)node * K + lane * 4];   // self loop
    __half2 a0 = cv.h[0], a1 = cv.h[1];
    __half2 b0 = __float2half2_rn(0.f), b1 = __float2half2_rn(0.f);
    int e = beg;
    for (; e + 8 <= end; e += 8) {
        int myc = col[e + (lane & 7)];
        uint2 v[8];
#pragma unroll
        for (int j = 0; j < 8; ++j) {
            int s = __shfl(myc, j, 16);
            v[j] = *(const uint2*)&hs[(size_t)s * K + lane * 4];
        }
#pragma unroll
        for (int j = 0; j < 8; j += 2) {
            union { uint2 u; __half2 h[2]; } c0, c1;
            c0.u = v[j]; c1.u = v[j + 1];
            a0 = __hadd2(a0, c0.h[0]); a1 = __hadd2(a1, c0.h[1]);
            b0 = __hadd2(b0, c1.h[0]); b1 = __hadd2(b1, c1.h[1]);
        }
    }
    {
        const int m = end - e;  // 0..7
        int myc = (e + (lane & 7) < end) ? col[e + (lane & 7)] : 0;
#pragma unroll
        for (int j = 0; j < 7; ++j) {
            if (j < m) {
                int s = __shfl(myc, j, 16);
                union { uint2 u; __half2 h[2]; } c0;
                c0.u = *(const uint2*)&hs[(size_t)s * K + lane * 4];
                a0 = __hadd2(a0, c0.h[0]); a1 = __hadd2(a1, c0.h[1]);
            }
        }
    }
    float2 fa0 = __half22float2(a0), fa1 = __half22float2(a1);
    float2 fb0 = __half22float2(b0), fb1 = __half22float2(b1);
    dv = dinv[node];
    float4 r;
    r.x = (fa0.x + fb0.x) * dv;
    r.y = (fa0.y + fb0.y) * dv;
    r.z = (fa1.x + fb1.x) * dv;
    r.w = (fa1.y + fb1.y) * dv;
    if (GBR) {
        float4 bv = *(const float4*)&gbias[lane * 4];
        r.x = fmaxf(r.x + bv.x, 0.f);
        r.y = fmaxf(r.y + bv.y, 0.f);
        r.z = fmaxf(r.z + bv.z, 0.f);
        r.w = fmaxf(r.w + bv.w, 0.f);
    }
    return r;
}

// Fused gather(64,fp16) + fp16-packed GEMM(64->OUT), 1 node per 16-lane group.
// W staged in LDS as half2 pairs; dot via v_dot2_f32_f16 (fp32 accum).
// GMODE 0: relu(acc+obias)->fp16 ; GMODE 1: acc*dinv->fp16.
template <int OUT, int NPB, bool GBR, int GMODE>
__launch_bounds__(NPB * 16)
static __global__ void fg_kernel(const __half* __restrict__ hs, const int* __restrict__ rowptr,
                                 const int* __restrict__ col, const float* __restrict__ dinv,
                                 const float* __restrict__ gbias, const float* __restrict__ W,
                                 const float* __restrict__ obias, __half* __restrict__ out, int N) {
    constexpr int K = 64;
    constexpr int NT = NPB * 16;
    constexpr int CPT = OUT / 16;          // 8 / 4 / 2
    __shared__ int Wl2[(K / 2) * OUT];     // half2-packed: (k,k+1) x col
    const int tid = threadIdx.x;

    for (int i = tid; i < (K / 2) * OUT; i += NT) {
        int c = i % OUT;
        int kk2 = i / OUT;
        Wl2[i] = pk2i(W[(size_t)(2 * kk2) * OUT + c], W[(size_t)(2 * kk2 + 1) * OUT + c]);
    }
    __syncthreads();   // only barrier: W resident

    const int lane = tid & 15;
    const int node = blockIdx.x * NPB + (tid >> 4);
    if (node >= N) return;

    float dv;
    float4 r = gather64<GBR>(hs, rowptr, col, dinv, gbias, node, lane, dv);

    int ip0 = pk2i(r.x, r.y);
    int ip1 = pk2i(r.z, r.w);

    float oacc[CPT];
#pragma unroll
    for (int c = 0; c < CPT; ++c) oacc[c] = 0.f;

#pragma unroll
    for (int src = 0; src < 16; ++src) {
        half2v a0 = i2h(__shfl(ip0, src, 16));   // k pair 2*src
        half2v a1 = i2h(__shfl(ip1, src, 16));   // k pair 2*src+1
        if (CPT >= 4) {
#pragma unroll
            for (int c = 0; c < CPT / 4; ++c) {
                int4 w0 = *(int4*)&Wl2[(2 * src) * OUT + c * 64 + lane * 4];
                int4 w1 = *(int4*)&Wl2[(2 * src + 1) * OUT + c * 64 + lane * 4];
                oacc[c * 4 + 0] = FDOT2(a0, i2h(w0.x), oacc[c * 4 + 0]);
                oacc[c * 4 + 1] = FDOT2(a0, i2h(w0.y), oacc[c * 4 + 1]);
                oacc[c * 4 + 2] = FDOT2(a0, i2h(w0.z), oacc[c * 4 + 2]);
                oacc[c * 4 + 3] = FDOT2(a0, i2h(w0.w), oacc[c * 4 + 3]);
                oacc[c * 4 + 0] = FDOT2(a1, i2h(w1.x), oacc[c * 4 + 0]);
                oacc[c * 4 + 1] = FDOT2(a1, i2h(w1.y), oacc[c * 4 + 1]);
                oacc[c * 4 + 2] = FDOT2(a1, i2h(w1.z), oacc[c * 4 + 2]);
                oacc[c * 4 + 3] = FDOT2(a1, i2h(w1.w), oacc[c * 4 + 3]);
            }
        } else {
            int2 w0 = *(int2*)&Wl2[(2 * src) * OUT + lane * 2];
            int2 w1 = *(int2*)&Wl2[(2 * src + 1) * OUT + lane * 2];
            oacc[0] = FDOT2(a0, i2h(w0.x), oacc[0]);
            oacc[1] = FDOT2(a0, i2h(w0.y), oacc[1]);
            oacc[0] = FDOT2(a1, i2h(w1.x), oacc[0]);
            oacc[1] = FDOT2(a1, i2h(w1.y), oacc[1]);
        }
    }

    if (GMODE == 0) {
#pragma unroll
        for (int c = 0; c < CPT / 4; ++c) {
            float4 bv = *(const float4*)&obias[c * 64 + lane * 4];
            float4 o;
            o.x = fmaxf(oacc[c * 4 + 0] + bv.x, 0.f);
            o.y = fmaxf(oacc[c * 4 + 1] + bv.y, 0.f);
            o.z = fmaxf(oacc[c * 4 + 2] + bv.z, 0.f);
            o.w = fmaxf(oacc[c * 4 + 3] + bv.w, 0.f);
            f4toh4(&out[(size_t)node * OUT + c * 64 + lane * 4], o);
        }
    } else {
        if (CPT >= 4) {
#pragma unroll
            for (int c = 0; c < CPT / 4; ++c) {
                float4 o;
                o.x = oacc[c * 4 + 0] * dv;
                o.y = oacc[c * 4 + 1] * dv;
                o.z = oacc[c * 4 + 2] * dv;
                o.w = oacc[c * 4 + 3] * dv;
                f4toh4(&out[(size_t)node * OUT + c * 64 + lane * 4], o);
            }
        } else {
            *(__half2*)&out[(size_t)node * OUT + lane * 2] =
                __floats2half2_rn(oacc[0] * dv, oacc[1] * dv);
        }
    }
}

// Fused gather(32,fp16) + b4/relu + dot(Wfc) + segment-mean pooling.
__launch_bounds__(256)
static __global__ void fg4_kernel(const __half* __restrict__ hs, const int* __restrict__ rowptr,
                                  const int* __restrict__ col, const float* __restrict__ dinv,
                                  const float* __restrict__ b4, const float* __restrict__ Wfc,
                                  const int* __restrict__ batch, float* __restrict__ psum,
                                  int* __restrict__ pcnt, int N) {
    constexpr int K = 32;
    __shared__ float wl[32];
    __shared__ float gsum[64];
    __shared__ int gcnt[64];
    __shared__ int sbase;
    const int tid = threadIdx.x;
    if (tid < 32) wl[tid] = Wfc[tid];
    if (tid < 64) { gsum[tid] = 0.f; gcnt[tid] = 0; }
    if (tid == 0) {
        int bi = (int)blockIdx.x * 32;
        if (bi > N - 1) bi = N - 1;
        sbase = batch[bi];
    }
    __syncthreads();

    const int lane = tid & 7;
    const int li = tid >> 3;
    const int node = blockIdx.x * 32 + li;
    float val = 0.f;
    if (node < N) {
        const int beg = rowptr[node];
        const int end = rowptr[node + 1];
        union { uint2 u; __half2 h[2]; } cv;
        cv.u = *(const uint2*)&hs[(size_t)node * K + lane * 4];
        __half2 a0 = cv.h[0], a1 = cv.h[1];
        __half2 b0h = __float2half2_rn(0.f), b1h = __float2half2_rn(0.f);
        int e = beg;
        for (; e + 8 <= end; e += 8) {
            int myc = col[e + lane];
            uint2 v[8];
#pragma unroll
            for (int j = 0; j < 8; ++j) {
                int s = __shfl(myc, j, 8);
                v[j] = *(const uint2*)&hs[(size_t)s * K + lane * 4];
            }
#pragma unroll
            for (int j = 0; j < 8; j += 2) {
                union { uint2 u; __half2 h[2]; } c0, c1;
                c0.u = v[j]; c1.u = v[j + 1];
                a0 = __hadd2(a0, c0.h[0]); a1 = __hadd2(a1, c0.h[1]);
                b0h = __hadd2(b0h, c1.h[0]); b1h = __hadd2(b1h, c1.h[1]);
            }
        }
        {
            const int m = end - e;
            int myc = (e + lane < end) ? col[e + lane] : 0;
#pragma unroll
            for (int j = 0; j < 7; ++j) {
                if (j < m) {
                    int s = __shfl(myc, j, 8);
                    union { uint2 u; __half2 h[2]; } c0;
                    c0.u = *(const uint2*)&hs[(size_t)s * K + lane * 4];
                    a0 = __hadd2(a0, c0.h[0]); a1 = __hadd2(a1, c0.h[1]);
                }
            }
        }
        float2 fa0 = __half22float2(a0), fa1 = __half22float2(a1);
        float2 fb0 = __half22float2(b0h), fb1 = __half22float2(b1h);
        float dv = dinv[node];
        float4 bv = *(const float4*)&b4[lane * 4];
        float4 h;
        h.x = fmaxf((fa0.x + fb0.x) * dv + bv.x, 0.f);
        h.y = fmaxf((fa0.y + fb0.y) * dv + bv.y, 0.f);
        h.z = fmaxf((fa1.x + fb1.x) * dv + bv.z, 0.f);
        h.w = fmaxf((fa1.y + fb1.y) * dv + bv.w, 0.f);
        val = h.x * wl[lane * 4 + 0] + h.y * wl[lane * 4 + 1] +
              h.z * wl[lane * 4 + 2] + h.w * wl[lane * 4 + 3];
    }
    val += __shfl_xor(val, 1, 8);
    val += __shfl_xor(val, 2, 8);
    val += __shfl_xor(val, 4, 8);
    if (node < N && lane == 0) {
        int g = batch[node];
        int rel = g - sbase;
        if ((unsigned)rel < 64u) {
            atomicAdd(&gsum[rel], val);
            atomicAdd(&gcnt[rel], 1);
        } else {
            unsafeAtomicAdd(&psum[g], val);
            atomicAdd(&pcnt[g], 1);
        }
    }
    __syncthreads();
    if (tid < 64 && gcnt[tid] > 0) {
        unsafeAtomicAdd(&psum[sbase + tid], gsum[tid]);
        atomicAdd(&pcnt[sbase + tid], gcnt[tid]);
    }
}

// out(fp16) = Xin(fp16) @ W(fp32) * dinv[row]. W in LDS. (gemm2 only)
template <int K, int OUT, int RT>
__launch_bounds__(256)
static __global__ void gemm_kernel(const __half* __restrict__ Xin, const float* __restrict__ W,
                                   const float* __restrict__ dinv, __half* __restrict__ out, int N) {
    constexpr int CT = OUT / 4;
    constexpr int RTH = 256 / CT;
    constexpr int RB = RTH * RT;
    constexpr int KP = K + 4;
    __shared__ float Wl[K * OUT];
    __shared__ float Xl[RB * KP];

    const int tid = threadIdx.x;
    const int row0 = blockIdx.x * RB;

    for (int idx = tid; idx < K * OUT / 4; idx += 256)
        ((float4*)Wl)[idx] = ((const float4*)W)[idx];

    constexpr int KC = K / 4;
    for (int idx = tid; idx < RB * KC; idx += 256) {
        int r = idx / KC;
        int kc = idx - r * KC;
        int g = row0 + r;
        float4 v = (g < N) ? h4tof4(&Xin[(size_t)g * K + kc * 4])
                           : make_float4(0.f, 0.f, 0.f, 0.f);
        *(float4*)&Xl[r * KP + kc * 4] = v;
    }
    __syncthreads();

    const int tx = tid % CT, ty = tid / CT;
    const int col0 = tx * 4;
    float4 acc[RT];
#pragma unroll
    for (int i = 0; i < RT; i++) acc[i] = make_float4(0.f, 0.f, 0.f, 0.f);

#pragma unroll 4
    for (int k = 0; k < K; k += 4) {
        float4 w0 = *(float4*)&Wl[(k + 0) * OUT + col0];
        float4 w1 = *(float4*)&Wl[(k + 1) * OUT + col0];
        float4 w2 = *(float4*)&Wl[(k + 2) * OUT + col0];
        float4 w3 = *(float4*)&Wl[(k + 3) * OUT + col0];
#pragma unroll
        for (int i = 0; i < RT; i++) {
            float4 xv = *(float4*)&Xl[(ty * RT + i) * KP + k];
            acc[i].x += xv.x * w0.x + xv.y * w1.x + xv.z * w2.x + xv.w * w3.x;
            acc[i].y += xv.x * w0.y + xv.y * w1.y + xv.z * w2.y + xv.w * w3.y;
            acc[i].z += xv.x * w0.z + xv.y * w1.z + xv.z * w2.z + xv.w * w3.z;
            acc[i].w += xv.x * w0.w + xv.y * w1.w + xv.z * w2.w + xv.w * w3.w;
        }
    }

#pragma unroll
    for (int i = 0; i < RT; i++) {
        int g = row0 + ty * RT + i;
        if (g < N) {
            float d = dinv[g];
            float4 r;
            r.x = acc[i].x * d; r.y = acc[i].y * d;
            r.z = acc[i].z * d; r.w = acc[i].w * d;
            f4toh4(&out[(size_t)g * OUT + col0], r);
        }
    }
}

static __global__ void final_kernel(const float* __restrict__ psum, const int* __restrict__ pcnt,
                                    const float* __restrict__ bfc, float* __restrict__ out, int G) {
    int t = threadIdx.x;
    if (t < G) {
        float c = (float)pcnt[t];
        out[t] = psum[t] / fmaxf(c, 1.f) + bfc[0];
    }
}

extern "C" void kernel_launch(void* const* d_in, const int* in_sizes, int n_in,
                              void* d_out, int out_size, void* d_ws, size_t ws_size,
                              hipStream_t stream) {
    const float* x    = (const float*)d_in[0];
    const int*   ei   = (const int*)d_in[1];
    const int*   batch= (const int*)d_in[2];
    const float* W1   = (const float*)d_in[4];
    const float* b1   = (const float*)d_in[5];
    const float* W2   = (const float*)d_in[6];
    const float* b2   = (const float*)d_in[7];
    const float* W3   = (const float*)d_in[8];
    const float* b3   = (const float*)d_in[9];
    const float* W4   = (const float*)d_in[10];
    const float* b4   = (const float*)d_in[11];
    const float* Wfc  = (const float*)d_in[12];
    const float* bfc  = (const float*)d_in[13];
    float* out = (float*)d_out;

    const int N = in_sizes[0] / 64;
    const int E = in_sizes[1] / 2;
    const int G = out_size;
    const int* srcp = ei;
    const int* dstp = ei + E;
    const int NB = (N + BKT_SZ - 1) >> BKT_LG;   // 391 for N=100k

    // workspace layout (float-sized slots)
    float* wsf = (float*)d_ws;
    const size_t Npad = ((size_t)N + 1023) / 1024 * 1024;
    const size_t Epad = ((size_t)E + 1023) / 1024 * 1024;
    float*    dinv   = wsf;                            // Npad
    int*      rowptr = (int*)(wsf + Npad);             // Npad + 1024
    int*      col    = (int*)(wsf + 2 * Npad + 1024);  // Epad
    unsigned* binned = (unsigned*)((float*)col + Epad);// Epad
    int*      bcnt   = (int*)((float*)binned + Epad);  // 512
    int*      base   = bcnt + 512;                     // 512
    int*      bfill  = base + 512;                     // 512
    float*    psum   = (float*)(bfill + 512);          // 256
    int*      pcnt   = (int*)(psum + 256);             // 256
    __half*   T1h    = (__half*)(psum + 1024);         // Npad*64 halves
    __half*   T2h    = (__half*)((float*)T1h + Npad * 32); // Npad*64 halves
    __half*   H1h    = (__half*)((float*)T2h + Npad * 32); // Npad*128 halves

    const int gN   = (N + 255) / 256;
    const int gN16 = (N * 16 + 255) / 256;
    const int nbin = (E + BIN_CHUNK - 1) / BIN_CHUNK;
    const int gBH  = (E + 2047) / 2048;   // bhist strided blocks
    const int gFG1 = (N + 31) / 32;   // 512 threads, 32 nodes
    const int gFG  = (N + 15) / 16;   // 256 threads, 16 nodes
    const int gFG4 = (N + 31) / 32;

    hipMemsetAsync(bcnt, 0, 512 * sizeof(int), stream);
    hipMemsetAsync(psum, 0, 512 * sizeof(float), stream);

    // ---- CSR build (by dst, col = src) + dinv
    bhist_kernel<<<gBH, 256, 0, stream>>>(dstp, bcnt, E, NB);
    bscan_kernel<<<1, 512, 0, stream>>>(bcnt, base, bfill, NB, E);
    bin_kernel<<<nbin, 256, 0, stream>>>(srcp, dstp, bfill, binned, E, NB);
    group_kernel<<<NB, 256, 0, stream>>>(binned, base, rowptr, col, dinv, N, E);

    // ---- layer 1: scale(fp16), fused gather+GEMM(64->128,+b1,relu) -> H1(fp16)
    scale_kernel<<<gN16, 256, 0, stream>>>(x, dinv, T1h, N);
    fg_kernel<128, 32, false, 0><<<gFG1, 512, 0, stream>>>(T1h, rowptr, col, dinv, nullptr, W1, b1, H1h, N);

    // ---- layer 2 GEMM: T2h = (H1h @ W2) * dinv  (fp16 out)
    gemm_kernel<128, 64, 2><<<(N + 31) / 32, 256, 0, stream>>>(H1h, W2, dinv, T2h, N);

    // ---- fused gather2(+b2,relu) + GEMM3(64->64, *dinv) -> T1h
    fg_kernel<64, 16, true, 1><<<gFG, 256, 0, stream>>>(T2h, rowptr, col, dinv, b2, W3, nullptr, T1h, N);

    // ---- fused gather3(+b3,relu) + GEMM4(64->32, *dinv) -> T2h (32-dim)
    fg_kernel<32, 16, true, 1><<<gFG, 256, 0, stream>>>(T1h, rowptr, col, dinv, b3, W4, nullptr, T2h, N);

    // ---- fused gather4(+b4,relu) + fc-dot + pooled segment sums
    fg4_kernel<<<gFG4, 256, 0, stream>>>(T2h, rowptr, col, dinv, b4, Wfc, batch, psum, pcnt, N);

    // ---- final mean + bias
    final_kernel<<<1, 256, 0, stream>>>(psum, pcnt, bfc, out, G);
}

// Round 18
// 355.039 us; speedup vs baseline: 3.2715x; 1.0129x over previous
//
#include <hip/hip_runtime.h>
#include <hip/hip_fp16.h>
#include <cstdint>
#include <cstddef>

// ---------------------------------------------------------------------------
// GCN regression. Round 18: fuse gemm2 (H1 @ W2 * dinv) into FG1.
//   FG1 now: gather(T1,64) -> @W1+b1,relu (H1 row stays in registers,
//   8 fp32/lane) -> packed-pair shfl broadcast -> @W2*dinv -> T2h.
//   Deletes the gemm2 dispatch and the 25.6MB H1 tensor round-trip.
//   LDS 32KB (W1+W2 packed half2) -> still 4x512-thread blocks/CU.
//   Everything else identical to R17 (360us).
// ---------------------------------------------------------------------------

#define BKT_LG 8
#define BKT_SZ 256
#define BIN_CHUNK 2048

using half2v = decltype(__builtin_amdgcn_cvt_pkrtz(0.0f, 0.0f));

#if __has_builtin(__builtin_amdgcn_fdot2)
#define FDOT2(a, b, c) __builtin_amdgcn_fdot2((a), (b), (c), false)
#else
__device__ __forceinline__ float fdot2_emul(half2v a, half2v b, float c) {
    return c + (float)a[0] * (float)b[0] + (float)a[1] * (float)b[1];
}
#define FDOT2(a, b, c) fdot2_emul((a), (b), (c))
#endif

__device__ __forceinline__ half2v i2h(int i) { union { int i; half2v h; } u; u.i = i; return u.h; }
__device__ __forceinline__ int h2i(half2v h) { union { int i; half2v h; } u; u.h = h; return u.i; }
__device__ __forceinline__ int pk2i(float a, float b) { return h2i(__builtin_amdgcn_cvt_pkrtz(a, b)); }

__device__ __forceinline__ float4 h4tof4(const __half* p) {
    union { uint2 u; __half2 h[2]; } cv;
    cv.u = *(const uint2*)p;
    float2 a = __half22float2(cv.h[0]);
    float2 b = __half22float2(cv.h[1]);
    return make_float4(a.x, a.y, b.x, b.y);
}
__device__ __forceinline__ void f4toh4(__half* p, float4 v) {
    union { uint2 u; __half2 h[2]; } cv;
    cv.h[0] = __floats2half2_rn(v.x, v.y);
    cv.h[1] = __floats2half2_rn(v.z, v.w);
    *(uint2*)p = cv.u;
}

// ---- bucket histogram: bcnt[b] = #edges with dst in bucket b
static __global__ void bhist_kernel(const int* __restrict__ dst, int* __restrict__ bcnt,
                                    int E, int NB) {
    __shared__ int h[512];
    for (int i = threadIdx.x; i < NB; i += 256) h[i] = 0;
    __syncthreads();
    for (int t = blockIdx.x * 256 + threadIdx.x; t < E; t += gridDim.x * 256)
        atomicAdd(&h[dst[t] >> BKT_LG], 1);
    __syncthreads();
    for (int i = threadIdx.x; i < NB; i += 256)
        if (h[i]) atomicAdd(&bcnt[i], h[i]);
}

// ---- exclusive scan of bcnt -> base (NB+1), bfill = base  (single block, 512)
static __global__ void bscan_kernel(const int* __restrict__ bcnt, int* __restrict__ base,
                                    int* __restrict__ bfill, int NB, int E) {
    __shared__ int s[512];
    int t = threadIdx.x;
    int v = (t < NB) ? bcnt[t] : 0;
    s[t] = v;
    __syncthreads();
    for (int off = 1; off < 512; off <<= 1) {
        int u = (t >= off) ? s[t - off] : 0;
        __syncthreads();
        s[t] += u;
        __syncthreads();
    }
    if (t < NB) { base[t] = s[t] - v; bfill[t] = s[t] - v; }
    if (t == 0) base[NB] = E;
}

// ---- bin edges into bucket-contiguous runs
__launch_bounds__(256)
static __global__ void bin_kernel(const int* __restrict__ src, const int* __restrict__ dst,
                                  int* __restrict__ bfill, unsigned* __restrict__ binned,
                                  int E, int NB) {
    __shared__ int h[512];
    __shared__ int res[512];
    const int beg = blockIdx.x * BIN_CHUNK;
    const int ce = min(BIN_CHUNK, E - beg);
    for (int i = threadIdx.x; i < NB; i += 256) h[i] = 0;
    __syncthreads();
    for (int i = threadIdx.x; i < ce; i += 256)
        atomicAdd(&h[dst[beg + i] >> BKT_LG], 1);
    __syncthreads();
    for (int i = threadIdx.x; i < NB; i += 256) {
        res[i] = h[i] ? atomicAdd(&bfill[i], h[i]) : 0;
        h[i] = 0;
    }
    __syncthreads();
    for (int i = threadIdx.x; i < ce; i += 256) {
        int d = dst[beg + i];
        int b = d >> BKT_LG;
        int p = res[b] + atomicAdd(&h[b], 1);
        binned[p] = ((unsigned)src[beg + i] << BKT_LG) | (unsigned)(d & (BKT_SZ - 1));
    }
}

// ---- per-bucket (256 nodes): count, scan, emit rowptr/dinv, group col
__launch_bounds__(256)
static __global__ void group_kernel(const unsigned* __restrict__ binned, const int* __restrict__ base,
                                    int* __restrict__ rowptr, int* __restrict__ col,
                                    float* __restrict__ dinv, int N, int E) {
    __shared__ int cnt[BKT_SZ];
    __shared__ int ex[BKT_SZ];
    __shared__ int ps[256];
    const int tid = threadIdx.x;
    const int b = blockIdx.x;
    const int node0 = b << BKT_LG;
    const int nn = min(BKT_SZ, N - node0);
    const int beg = base[b], end = base[b + 1];

    cnt[tid] = 0;
    __syncthreads();
    for (int i = beg + tid; i < end; i += 256)
        atomicAdd(&cnt[binned[i] & (BKT_SZ - 1)], 1);
    __syncthreads();

    int c = cnt[tid];
    ps[tid] = c;
    __syncthreads();
    for (int off = 1; off < 256; off <<= 1) {
        int u = (tid >= off) ? ps[tid - off] : 0;
        __syncthreads();
        ps[tid] += u;
        __syncthreads();
    }
    int excl = ps[tid] - c;
    ex[tid] = excl;
    __syncthreads();

    if (tid < nn) {
        rowptr[node0 + tid] = beg + excl;
        dinv[node0 + tid] = rsqrtf((float)c + 1.0f);
    }
    if (b == 0 && tid == 0) rowptr[N] = E;
    __syncthreads();

    for (int i = beg + tid; i < end; i += 256) {
        unsigned v = binned[i];
        int dl = v & (BKT_SZ - 1);
        int p = atomicAdd(&ex[dl], 1);
        col[beg + p] = (int)(v >> BKT_LG);
    }
}

// o[row] = (half) x[row] * dinv[row], dim 64
static __global__ void scale_kernel(const float* __restrict__ x, const float* __restrict__ dinv,
                                    __half* __restrict__ o, int N) {
    int t = blockIdx.x * 256 + threadIdx.x;
    if (t >= N * 16) return;
    int row = t >> 4;
    int c = (t & 15) * 4;
    float d = dinv[row];
    float4 v = *(const float4*)&x[(size_t)row * 64 + c];
    v.x *= d; v.y *= d; v.z *= d; v.w *= d;
    f4toh4(&o[(size_t)row * 64 + c], v);
}

// gather one 64-dim fp16 node row slice for this lane (16-lane group).
// Packed-fp16 accumulation, dual accumulator pairs, fp32 combine at the end;
// dinv scale [+gbias relu]. Sets dv.
template <bool GBR>
__device__ __forceinline__ float4 gather64(const __half* __restrict__ hs,
                                           const int* __restrict__ rowptr,
                                           const int* __restrict__ col,
                                           const float* __restrict__ dinv,
                                           const float* __restrict__ gbias,
                                           int node, int lane, float& dv) {
    constexpr int K = 64;
    const int beg = rowptr[node];
    const int end = rowptr[node + 1];
    union { uint2 u; __half2 h[2]; } cv;
    cv.u = *(const uint2*)&hs[(size_t)node * K + lane * 4];   // self loop
    __half2 a0 = cv.h[0], a1 = cv.h[1];
    __half2 b0 = __float2half2_rn(0.f), b1 = __float2half2_rn(0.f);
    int e = beg;
    for (; e + 8 <= end; e += 8) {
        int myc = col[e + (lane & 7)];
        uint2 v[8];
#pragma unroll
        for (int j = 0; j < 8; ++j) {
            int s = __shfl(myc, j, 16);
            v[j] = *(const uint2*)&hs[(size_t)s * K + lane * 4];
        }
#pragma unroll
        for (int j = 0; j < 8; j += 2) {
            union { uint2 u; __half2 h[2]; } c0, c1;
            c0.u = v[j]; c1.u = v[j + 1];
            a0 = __hadd2(a0, c0.h[0]); a1 = __hadd2(a1, c0.h[1]);
            b0 = __hadd2(b0, c1.h[0]); b1 = __hadd2(b1, c1.h[1]);
        }
    }
    {
        const int m = end - e;  // 0..7
        int myc = (e + (lane & 7) < end) ? col[e + (lane & 7)] : 0;
#pragma unroll
        for (int j = 0; j < 7; ++j) {
            if (j < m) {
                int s = __shfl(myc, j, 16);
                union { uint2 u; __half2 h[2]; } c0;
                c0.u = *(const uint2*)&hs[(size_t)s * K + lane * 4];
                a0 = __hadd2(a0, c0.h[0]); a1 = __hadd2(a1, c0.h[1]);
            }
        }
    }
    float2 fa0 = __half22float2(a0), fa1 = __half22float2(a1);
    float2 fb0 = __half22float2(b0), fb1 = __half22float2(b1);
    dv = dinv[node];
    float4 r;
    r.x = (fa0.x + fb0.x) * dv;
    r.y = (fa0.y + fb0.y) * dv;
    r.z = (fa1.x + fb1.x) * dv;
    r.w = (fa1.y + fb1.y) * dv;
    if (GBR) {
        float4 bv = *(const float4*)&gbias[lane * 4];
        r.x = fmaxf(r.x + bv.x, 0.f);
        r.y = fmaxf(r.y + bv.y, 0.f);
        r.z = fmaxf(r.z + bv.z, 0.f);
        r.w = fmaxf(r.w + bv.w, 0.f);
    }
    return r;
}

// FG1 fused: gather(T1,64) -> GEMM1(64->128)+b1+relu (regs) -> GEMM2(128->64)
// *dinv -> T2h. 32 nodes x 16 lanes = 512 threads. W1,W2 packed half2 in LDS.
__launch_bounds__(512)
static __global__ void fg1_kernel(const __half* __restrict__ hs, const int* __restrict__ rowptr,
                                  const int* __restrict__ col, const float* __restrict__ dinv,
                                  const float* __restrict__ W1, const float* __restrict__ b1,
                                  const float* __restrict__ W2, __half* __restrict__ out, int N) {
    __shared__ int WA[32 * 128];   // W1 packed: kpair (k=64) x col (128) -> 16 KB
    __shared__ int WB[64 * 64];    // W2 packed: kpair (k=128) x col (64) -> 16 KB
    const int tid = threadIdx.x;

    for (int i = tid; i < 32 * 128; i += 512) {
        int c = i % 128, kk2 = i / 128;
        WA[i] = pk2i(W1[(size_t)(2 * kk2) * 128 + c], W1[(size_t)(2 * kk2 + 1) * 128 + c]);
    }
    for (int i = tid; i < 64 * 64; i += 512) {
        int c = i % 64, kk2 = i / 64;
        WB[i] = pk2i(W2[(size_t)(2 * kk2) * 64 + c], W2[(size_t)(2 * kk2 + 1) * 64 + c]);
    }
    __syncthreads();

    const int lane = tid & 15;
    const int node = blockIdx.x * 32 + (tid >> 4);
    if (node >= N) return;

    float dv;
    float4 r = gather64<false>(hs, rowptr, col, dinv, nullptr, node, lane, dv);
    int ip0 = pk2i(r.x, r.y);
    int ip1 = pk2i(r.z, r.w);

    // ---- GEMM1: 64 -> 128, CPT=8
    float oacc[8];
#pragma unroll
    for (int c = 0; c < 8; ++c) oacc[c] = 0.f;
#pragma unroll
    for (int src = 0; src < 16; ++src) {
        half2v a0 = i2h(__shfl(ip0, src, 16));
        half2v a1 = i2h(__shfl(ip1, src, 16));
#pragma unroll
        for (int c = 0; c < 2; ++c) {
            int4 w0 = *(int4*)&WA[(2 * src) * 128 + c * 64 + lane * 4];
            int4 w1 = *(int4*)&WA[(2 * src + 1) * 128 + c * 64 + lane * 4];
            oacc[c * 4 + 0] = FDOT2(a0, i2h(w0.x), oacc[c * 4 + 0]);
            oacc[c * 4 + 1] = FDOT2(a0, i2h(w0.y), oacc[c * 4 + 1]);
            oacc[c * 4 + 2] = FDOT2(a0, i2h(w0.z), oacc[c * 4 + 2]);
            oacc[c * 4 + 3] = FDOT2(a0, i2h(w0.w), oacc[c * 4 + 3]);
            oacc[c * 4 + 0] = FDOT2(a1, i2h(w1.x), oacc[c * 4 + 0]);
            oacc[c * 4 + 1] = FDOT2(a1, i2h(w1.y), oacc[c * 4 + 1]);
            oacc[c * 4 + 2] = FDOT2(a1, i2h(w1.z), oacc[c * 4 + 2]);
            oacc[c * 4 + 3] = FDOT2(a1, i2h(w1.w), oacc[c * 4 + 3]);
        }
    }

    // ---- epilogue1: +b1, relu, pack. Lane holds H1 cols {4l..4l+3, 64+4l..64+4l+3}
    //      hp0 = kpair 2*lane, hp1 = kpair 2*lane+1, hp2 = kpair 32+2*lane, hp3 = 33+2*lane
    float4 bv0 = *(const float4*)&b1[lane * 4];
    float4 bv1 = *(const float4*)&b1[64 + lane * 4];
    float h0 = fmaxf(oacc[0] + bv0.x, 0.f);
    float h1 = fmaxf(oacc[1] + bv0.y, 0.f);
    float h2 = fmaxf(oacc[2] + bv0.z, 0.f);
    float h3 = fmaxf(oacc[3] + bv0.w, 0.f);
    float h4 = fmaxf(oacc[4] + bv1.x, 0.f);
    float h5 = fmaxf(oacc[5] + bv1.y, 0.f);
    float h6 = fmaxf(oacc[6] + bv1.z, 0.f);
    float h7 = fmaxf(oacc[7] + bv1.w, 0.f);
    int hp0 = pk2i(h0, h1);
    int hp1 = pk2i(h2, h3);
    int hp2 = pk2i(h4, h5);
    int hp3 = pk2i(h6, h7);

    // ---- GEMM2: 128 -> 64, CPT=4
    float o2[4];
#pragma unroll
    for (int c = 0; c < 4; ++c) o2[c] = 0.f;
#pragma unroll
    for (int src = 0; src < 16; ++src) {
        half2v g0 = i2h(__shfl(hp0, src, 16));   // kpair 2*src
        half2v g1 = i2h(__shfl(hp1, src, 16));   // kpair 2*src+1
        half2v g2 = i2h(__shfl(hp2, src, 16));   // kpair 32+2*src
        half2v g3 = i2h(__shfl(hp3, src, 16));   // kpair 33+2*src
        int4 w0 = *(int4*)&WB[(2 * src) * 64 + lane * 4];
        int4 w1 = *(int4*)&WB[(2 * src + 1) * 64 + lane * 4];
        int4 w2 = *(int4*)&WB[(32 + 2 * src) * 64 + lane * 4];
        int4 w3 = *(int4*)&WB[(33 + 2 * src) * 64 + lane * 4];
        o2[0] = FDOT2(g0, i2h(w0.x), o2[0]); o2[1] = FDOT2(g0, i2h(w0.y), o2[1]);
        o2[2] = FDOT2(g0, i2h(w0.z), o2[2]); o2[3] = FDOT2(g0, i2h(w0.w), o2[3]);
        o2[0] = FDOT2(g1, i2h(w1.x), o2[0]); o2[1] = FDOT2(g1, i2h(w1.y), o2[1]);
        o2[2] = FDOT2(g1, i2h(w1.z), o2[2]); o2[3] = FDOT2(g1, i2h(w1.w), o2[3]);
        o2[0] = FDOT2(g2, i2h(w2.x), o2[0]); o2[1] = FDOT2(g2, i2h(w2.y), o2[1]);
        o2[2] = FDOT2(g2, i2h(w2.z), o2[2]); o2[3] = FDOT2(g2, i2h(w2.w), o2[3]);
        o2[0] = FDOT2(g3, i2h(w3.x), o2[0]); o2[1] = FDOT2(g3, i2h(w3.y), o2[1]);
        o2[2] = FDOT2(g3, i2h(w3.z), o2[2]); o2[3] = FDOT2(g3, i2h(w3.w), o2[3]);
    }

    float4 o;
    o.x = o2[0] * dv; o.y = o2[1] * dv; o.z = o2[2] * dv; o.w = o2[3] * dv;
    f4toh4(&out[(size_t)node * 64 + lane * 4], o);
}

// Fused gather(64,fp16) + fp16-packed GEMM(64->OUT), 1 node per 16-lane group.
// GMODE 1: acc*dinv->fp16 (used for FG2 OUT=64 and FG3 OUT=32).
template <int OUT, int NPB, bool GBR, int GMODE>
__launch_bounds__(NPB * 16)
static __global__ void fg_kernel(const __half* __restrict__ hs, const int* __restrict__ rowptr,
                                 const int* __restrict__ col, const float* __restrict__ dinv,
                                 const float* __restrict__ gbias, const float* __restrict__ W,
                                 const float* __restrict__ obias, __half* __restrict__ out, int N) {
    constexpr int K = 64;
    constexpr int NT = NPB * 16;
    constexpr int CPT = OUT / 16;          // 4 / 2
    __shared__ int Wl2[(K / 2) * OUT];
    const int tid = threadIdx.x;

    for (int i = tid; i < (K / 2) * OUT; i += NT) {
        int c = i % OUT;
        int kk2 = i / OUT;
        Wl2[i] = pk2i(W[(size_t)(2 * kk2) * OUT + c], W[(size_t)(2 * kk2 + 1) * OUT + c]);
    }
    __syncthreads();

    const int lane = tid & 15;
    const int node = blockIdx.x * NPB + (tid >> 4);
    if (node >= N) return;

    float dv;
    float4 r = gather64<GBR>(hs, rowptr, col, dinv, gbias, node, lane, dv);

    int ip0 = pk2i(r.x, r.y);
    int ip1 = pk2i(r.z, r.w);

    float oacc[CPT];
#pragma unroll
    for (int c = 0; c < CPT; ++c) oacc[c] = 0.f;

#pragma unroll
    for (int src = 0; src < 16; ++src) {
        half2v a0 = i2h(__shfl(ip0, src, 16));
        half2v a1 = i2h(__shfl(ip1, src, 16));
        if (CPT >= 4) {
#pragma unroll
            for (int c = 0; c < CPT / 4; ++c) {
                int4 w0 = *(int4*)&Wl2[(2 * src) * OUT + c * 64 + lane * 4];
                int4 w1 = *(int4*)&Wl2[(2 * src + 1) * OUT + c * 64 + lane * 4];
                oacc[c * 4 + 0] = FDOT2(a0, i2h(w0.x), oacc[c * 4 + 0]);
                oacc[c * 4 + 1] = FDOT2(a0, i2h(w0.y), oacc[c * 4 + 1]);
                oacc[c * 4 + 2] = FDOT2(a0, i2h(w0.z), oacc[c * 4 + 2]);
                oacc[c * 4 + 3] = FDOT2(a0, i2h(w0.w), oacc[c * 4 + 3]);
                oacc[c * 4 + 0] = FDOT2(a1, i2h(w1.x), oacc[c * 4 + 0]);
                oacc[c * 4 + 1] = FDOT2(a1, i2h(w1.y), oacc[c * 4 + 1]);
                oacc[c * 4 + 2] = FDOT2(a1, i2h(w1.z), oacc[c * 4 + 2]);
                oacc[c * 4 + 3] = FDOT2(a1, i2h(w1.w), oacc[c * 4 + 3]);
            }
        } else {
            int2 w0 = *(int2*)&Wl2[(2 * src) * OUT + lane * 2];
            int2 w1 = *(int2*)&Wl2[(2 * src + 1) * OUT + lane * 2];
            oacc[0] = FDOT2(a0, i2h(w0.x), oacc[0]);
            oacc[1] = FDOT2(a0, i2h(w0.y), oacc[1]);
            oacc[0] = FDOT2(a1, i2h(w1.x), oacc[0]);
            oacc[1] = FDOT2(a1, i2h(w1.y), oacc[1]);
        }
    }

    if (CPT >= 4) {
#pragma unroll
        for (int c = 0; c < CPT / 4; ++c) {
            float4 o;
            o.x = oacc[c * 4 + 0] * dv;
            o.y = oacc[c * 4 + 1] * dv;
            o.z = oacc[c * 4 + 2] * dv;
            o.w = oacc[c * 4 + 3] * dv;
            f4toh4(&out[(size_t)node * OUT + c * 64 + lane * 4], o);
        }
    } else {
        *(__half2*)&out[(size_t)node * OUT + lane * 2] =
            __floats2half2_rn(oacc[0] * dv, oacc[1] * dv);
    }
}

// Fused gather(32,fp16) + b4/relu + dot(Wfc) + segment-mean pooling.
__launch_bounds__(256)
static __global__ void fg4_kernel(const __half* __restrict__ hs, const int* __restrict__ rowptr,
                                  const int* __restrict__ col, const float* __restrict__ dinv,
                                  const float* __restrict__ b4, const float* __restrict__ Wfc,
                                  const int* __restrict__ batch, float* __restrict__ psum,
                                  int* __restrict__ pcnt, int N) {
    constexpr int K = 32;
    __shared__ float wl[32];
    __shared__ float gsum[64];
    __shared__ int gcnt[64];
    __shared__ int sbase;
    const int tid = threadIdx.x;
    if (tid < 32) wl[tid] = Wfc[tid];
    if (tid < 64) { gsum[tid] = 0.f; gcnt[tid] = 0; }
    if (tid == 0) {
        int bi = (int)blockIdx.x * 32;
        if (bi > N - 1) bi = N - 1;
        sbase = batch[bi];
    }
    __syncthreads();

    const int lane = tid & 7;
    const int li = tid >> 3;
    const int node = blockIdx.x * 32 + li;
    float val = 0.f;
    if (node < N) {
        const int beg = rowptr[node];
        const int end = rowptr[node + 1];
        union { uint2 u; __half2 h[2]; } cv;
        cv.u = *(const uint2*)&hs[(size_t)node * K + lane * 4];
        __half2 a0 = cv.h[0], a1 = cv.h[1];
        __half2 b0h = __float2half2_rn(0.f), b1h = __float2half2_rn(0.f);
        int e = beg;
        for (; e + 8 <= end; e += 8) {
            int myc = col[e + lane];
            uint2 v[8];
#pragma unroll
            for (int j = 0; j < 8; ++j) {
                int s = __shfl(myc, j, 8);
                v[j] = *(const uint2*)&hs[(size_t)s * K + lane * 4];
            }
#pragma unroll
            for (int j = 0; j < 8; j += 2) {
                union { uint2 u; __half2 h[2]; } c0, c1;
                c0.u = v[j]; c1.u = v[j + 1];
                a0 = __hadd2(a0, c0.h[0]); a1 = __hadd2(a1, c0.h[1]);
                b0h = __hadd2(b0h, c1.h[0]); b1h = __hadd2(b1h, c1.h[1]);
            }
        }
        {
            const int m = end - e;
            int myc = (e + lane < end) ? col[e + lane] : 0;
#pragma unroll
            for (int j = 0; j < 7; ++j) {
                if (j < m) {
                    int s = __shfl(myc, j, 8);
                    union { uint2 u; __half2 h[2]; } c0;
                    c0.u = *(const uint2*)&hs[(size_t)s * K + lane * 4];
                    a0 = __hadd2(a0, c0.h[0]); a1 = __hadd2(a1, c0.h[1]);
                }
            }
        }
        float2 fa0 = __half22float2(a0), fa1 = __half22float2(a1);
        float2 fb0 = __half22float2(b0h), fb1 = __half22float2(b1h);
        float dv = dinv[node];
        float4 bv = *(const float4*)&b4[lane * 4];
        float4 h;
        h.x = fmaxf((fa0.x + fb0.x) * dv + bv.x, 0.f);
        h.y = fmaxf((fa0.y + fb0.y) * dv + bv.y, 0.f);
        h.z = fmaxf((fa1.x + fb1.x) * dv + bv.z, 0.f);
        h.w = fmaxf((fa1.y + fb1.y) * dv + bv.w, 0.f);
        val = h.x * wl[lane * 4 + 0] + h.y * wl[lane * 4 + 1] +
              h.z * wl[lane * 4 + 2] + h.w * wl[lane * 4 + 3];
    }
    val += __shfl_xor(val, 1, 8);
    val += __shfl_xor(val, 2, 8);
    val += __shfl_xor(val, 4, 8);
    if (node < N && lane == 0) {
        int g = batch[node];
        int rel = g - sbase;
        if ((unsigned)rel < 64u) {
            atomicAdd(&gsum[rel], val);
            atomicAdd(&gcnt[rel], 1);
        } else {
            unsafeAtomicAdd(&psum[g], val);
            atomicAdd(&pcnt[g], 1);
        }
    }
    __syncthreads();
    if (tid < 64 && gcnt[tid] > 0) {
        unsafeAtomicAdd(&psum[sbase + tid], gsum[tid]);
        atomicAdd(&pcnt[sbase + tid], gcnt[tid]);
    }
}

static __global__ void final_kernel(const float* __restrict__ psum, const int* __restrict__ pcnt,
                                    const float* __restrict__ bfc, float* __restrict__ out, int G) {
    int t = threadIdx.x;
    if (t < G) {
        float c = (float)pcnt[t];
        out[t] = psum[t] / fmaxf(c, 1.f) + bfc[0];
    }
}

extern "C" void kernel_launch(void* const* d_in, const int* in_sizes, int n_in,
                              void* d_out, int out_size, void* d_ws, size_t ws_size,
                              hipStream_t stream) {
    const float* x    = (const float*)d_in[0];
    const int*   ei   = (const int*)d_in[1];
    const int*   batch= (const int*)d_in[2];
    const float* W1   = (const float*)d_in[4];
    const float* b1   = (const float*)d_in[5];
    const float* W2   = (const float*)d_in[6];
    const float* b2   = (const float*)d_in[7];
    const float* W3   = (const float*)d_in[8];
    const float* b3   = (const float*)d_in[9];
    const float* W4   = (const float*)d_in[10];
    const float* b4   = (const float*)d_in[11];
    const float* Wfc  = (const float*)d_in[12];
    const float* bfc  = (const float*)d_in[13];
    float* out = (float*)d_out;

    const int N = in_sizes[0] / 64;
    const int E = in_sizes[1] / 2;
    const int G = out_size;
    const int* srcp = ei;
    const int* dstp = ei + E;
    const int NB = (N + BKT_SZ - 1) >> BKT_LG;   // 391 for N=100k

    // workspace layout (float-sized slots)
    float* wsf = (float*)d_ws;
    const size_t Npad = ((size_t)N + 1023) / 1024 * 1024;
    const size_t Epad = ((size_t)E + 1023) / 1024 * 1024;
    float*    dinv   = wsf;                            // Npad
    int*      rowptr = (int*)(wsf + Npad);             // Npad + 1024
    int*      col    = (int*)(wsf + 2 * Npad + 1024);  // Epad
    unsigned* binned = (unsigned*)((float*)col + Epad);// Epad
    int*      bcnt   = (int*)((float*)binned + Epad);  // 512
    int*      base   = bcnt + 512;                     // 512
    int*      bfill  = base + 512;                     // 512
    float*    psum   = (float*)(bfill + 512);          // 256
    int*      pcnt   = (int*)(psum + 256);             // 256
    __half*   T1h    = (__half*)(psum + 1024);         // Npad*64 halves
    __half*   T2h    = (__half*)((float*)T1h + Npad * 32); // Npad*64 halves

    const int gN16 = (N * 16 + 255) / 256;
    const int nbin = (E + BIN_CHUNK - 1) / BIN_CHUNK;
    const int gBH  = (E + 2047) / 2048;
    const int gFG1 = (N + 31) / 32;   // 512 threads, 32 nodes
    const int gFG  = (N + 15) / 16;   // 256 threads, 16 nodes
    const int gFG4 = (N + 31) / 32;

    hipMemsetAsync(bcnt, 0, 512 * sizeof(int), stream);
    hipMemsetAsync(psum, 0, 512 * sizeof(float), stream);

    // ---- CSR build (by dst, col = src) + dinv
    bhist_kernel<<<gBH, 256, 0, stream>>>(dstp, bcnt, E, NB);
    bscan_kernel<<<1, 512, 0, stream>>>(bcnt, base, bfill, NB, E);
    bin_kernel<<<nbin, 256, 0, stream>>>(srcp, dstp, bfill, binned, E, NB);
    group_kernel<<<NB, 256, 0, stream>>>(binned, base, rowptr, col, dinv, N, E);

    // ---- layer 1+2: scale(fp16), fused gather + GEMM1(+b1,relu) + GEMM2(*dinv) -> T2h
    scale_kernel<<<gN16, 256, 0, stream>>>(x, dinv, T1h, N);
    fg1_kernel<<<gFG1, 512, 0, stream>>>(T1h, rowptr, col, dinv, W1, b1, W2, T2h, N);

    // ---- fused gather2(+b2,relu) + GEMM3(64->64, *dinv) -> T1h
    fg_kernel<64, 16, true, 1><<<gFG, 256, 0, stream>>>(T2h, rowptr, col, dinv, b2, W3, nullptr, T1h, N);

    // ---- fused gather3(+b3,relu) + GEMM4(64->32, *dinv) -> T2h (32-dim)
    fg_kernel<32, 16, true, 1><<<gFG, 256, 0, stream>>>(T1h, rowptr, col, dinv, b3, W4, nullptr, T2h, N);

    // ---- fused gather4(+b4,relu) + fc-dot + pooled segment sums
    fg4_kernel<<<gFG4, 256, 0, stream>>>(T2h, rowptr, col, dinv, b4, Wfc, batch, psum, pcnt, N);

    // ---- final mean + bias
    final_kernel<<<1, 256, 0, stream>>>(psum, pcnt, bfc, out, G);
}